// Round 10
// baseline (483.602 us; speedup 1.0000x reference)
//
#include <hip/hip_runtime.h>
#include <math.h>

// ---------------------------------------------------------------------------
// TGAT classifier. Algebraic folding (score/aggregate in input space,
// wq/wk/wv/W_lin/fc_w folded into SW/F), f16 MFMA everywhere.
// Round 10: 8 launches.
//   L1 k_prep_a    {cbf, prepM, build_OW, converts}
//   L2 k_prep_b    {build_SW, build_F, linS, lin1, xwT}
//   L3 k_l3        {U-A (A-resident), U-B, zb split-K=8}
//   L4 score_multi {score-A, score-B, zcomb}
//   L5 tail_loss   {tail-A, tail-B, loss}   <- tail LDS diet: 55.8->36.4 KB
//   L6 gemm_multi  {U-C, final-loss-write}
//   L7 score_multi {score-C}
//   L8 tail_loss   {tail-C}
// ---------------------------------------------------------------------------

typedef _Float16 h2 __attribute__((ext_vector_type(2)));
typedef _Float16 h4 __attribute__((ext_vector_type(4)));
typedef _Float16 h8 __attribute__((ext_vector_type(8)));
typedef float f4 __attribute__((ext_vector_type(4)));

// ============================ L1: independent prep ==========================

__global__ __launch_bounds__(256) void k_prep_a(
    const float* __restrict__ phase, const float* __restrict__ wq,
    const float* __restrict__ wk, const float* __restrict__ wvw,
    const float* __restrict__ Wlin, const float* __restrict__ blin,
    const float* __restrict__ m1w, const float* __restrict__ m2w,
    const float* __restrict__ Wgc,
    float* __restrict__ te0, float* __restrict__ cbf, float* __restrict__ Mb,
    float* __restrict__ OWa,
    _Float16* __restrict__ Wlinh, _Float16* __restrict__ m1wh,
    _Float16* __restrict__ m2wh, _Float16* __restrict__ WgcTh,
    float* __restrict__ lacc)
{
  __shared__ float te[128];
  __shared__ float bqv[128];
  int b = blockIdx.x, tid = threadIdx.x;

  if (b < 4) {
    int l = b >> 1, h = b & 1;
    if (tid < 128) {
      te[tid] = cosf(phase[tid]);
      if (b == 0) te0[tid] = te[tid];
    }
    __syncthreads();
    if (tid < 128) {
      const float* wr = wq + ((size_t)(l * 256 + h * 128 + tid)) * 256 + 128;
      float s = 0.f;
      for (int k = 0; k < 128; k++) s += wr[k] * te[k];
      bqv[tid] = s;
    }
    __syncthreads();
    {
      const float* wkb = wk + (size_t)l * 65536 + (size_t)h * 32768;
      float s = 0.f;
      for (int d = 0; d < 128; d++) s += wkb[(size_t)d * 256 + tid] * bqv[d];
      cbf[(l * 2 + h) * 256 + tid] = s;
    }
    return;
  }
  b -= 4;
  if (b < 512) {   // prepM
    int lh = b >> 7, bx = b & 127;
    int l = lh >> 1, h = lh & 1;
    int idx = bx * 256 + tid;
    int e = idx >> 7, s = idx & 127;
    const float* wkb = wk + (size_t)l * 65536 + (size_t)h * 32768;
    const float* wqb = wq + (size_t)l * 65536 + (size_t)h * 32768;
    float acc = 0.f;
    for (int d = 0; d < 128; d++)
      acc += wkb[(size_t)d * 256 + e] * wqb[(size_t)d * 256 + s];
    Mb[(size_t)lh * 32768 + idx] = acc;
    return;
  }
  b -= 512;
  if (b < 780) {   // build_OW
    int ci = b / 260, bx = b % 260;
    int lyr = (ci == 2) ? 1 : 0;
    int ul  = (ci == 0) ? 1 : 0;
    float* OW = OWa + (size_t)ci * 2 * 128 * 260;
    const float* wvl = wvw + (size_t)lyr * 65536;
    int idx = bx * 256 + tid;
    int u = idx % 260; int d = (idx / 260) % 128; int h = idx / (260 * 128);
    const float* wr = wvl + (size_t)(h * 128 + d) * 256;
    float val = 0.f;
    if (u < 128) {
      if (ul) { for (int cc = 0; cc < 128; cc++) val += wr[cc] * Wlin[cc * 128 + u]; }
      else val = wr[u];
    } else if (u < 256) {
      val = wr[u];
    } else if (u == 256) {
      if (ul) { for (int cc = 0; cc < 128; cc++) val += wr[cc] * blin[cc]; }
    }
    OW[idx] = val;
    return;
  }
  b -= 780;
  {  // converts + lacc zero (640 blocks)
    int idx = b * 256 + tid;
    if (idx == 0) lacc[0] = 0.f;
    int i = idx;
    if (i < 16384) { Wlinh[i] = (_Float16)Wlin[i]; return; }
    i -= 16384;
    if (i < 98304) { m1wh[i] = (_Float16)m1w[i]; return; }
    i -= 98304;
    if (i < 32768) { m2wh[i] = (_Float16)m2w[i]; return; }
    i -= 32768;
    {
      int c = i >> 7, r = i & 127;
      WgcTh[i] = (_Float16)Wgc[(size_t)r * 128 + c];
    }
  }
}

// ===================== shared f16 MFMA GEMM body ============================

struct GemmJob {
  const float* A; const _Float16* B; const float* bias; float* C;
  int lda, ldb, ldc, M, N, K, cmode, klen, gx, gy, nblk;
};

__device__ __forceinline__ void gemm128_body(int lb, const GemmJob& g) {
  __shared__ _Float16 As[128][72];
  __shared__ _Float16 Bs[128][72];
  int bx = lb % g.gx;
  int rest = lb / g.gx;
  int by = rest % g.gy;
  int z = rest / g.gy;

  int tid = threadIdx.x;
  int wv = tid >> 6, lane = tid & 63;
  int wm = wv >> 1, wn = wv & 1;
  int row0 = bx * 128, col0 = by * 128;
  int m0 = wm * 64, n0 = wn * 64;
  int lr = lane & 15, lk = lane >> 4;
  int kbeg = z * g.klen;
  int kend = kbeg + g.klen; if (kend > g.K) kend = g.K;

  f4 acc[4][4];
#pragma unroll
  for (int i = 0; i < 4; i++)
#pragma unroll
    for (int j = 0; j < 4; j++) acc[i][j] = (f4)0.f;

  int arow = tid >> 1;
  int acol = (tid & 1) * 32;
  int gar = row0 + arow;
  int gbr = col0 + arow;
  bool bvalid = gbr < g.N;

  for (int k0 = kbeg; k0 < kend; k0 += 64) {
    __syncthreads();
#pragma unroll
    for (int j = 0; j < 8; j++) {
      int ka = k0 + acol + j * 4;
      f4 v = (f4)0.f;
      if (ka < g.K) v = *(const f4*)&g.A[(size_t)gar * g.lda + ka];
      h4 hv = { (_Float16)v.x, (_Float16)v.y, (_Float16)v.z, (_Float16)v.w };
      *(h4*)&As[arow][acol + j * 4] = hv;
    }
#pragma unroll
    for (int j = 0; j < 8; j++) {
      int ka = k0 + acol + j * 4;
      h4 hv = (h4)(_Float16)0.f;
      if (bvalid && ka < g.K) hv = *(const h4*)&g.B[(size_t)gbr * g.ldb + ka];
      *(h4*)&Bs[arow][acol + j * 4] = hv;
    }
    __syncthreads();
#pragma unroll
    for (int kk = 0; kk < 2; kk++) {
      h8 af[4], bf[4];
#pragma unroll
      for (int i = 0; i < 4; i++)
        af[i] = *(h8*)&As[m0 + i * 16 + lr][kk * 32 + lk * 8];
#pragma unroll
      for (int j = 0; j < 4; j++)
        bf[j] = *(h8*)&Bs[n0 + j * 16 + lr][kk * 32 + lk * 8];
#pragma unroll
      for (int i = 0; i < 4; i++)
#pragma unroll
        for (int j = 0; j < 4; j++)
          acc[i][j] = __builtin_amdgcn_mfma_f32_16x16x32_f16(af[i], bf[j], acc[i][j], 0, 0, 0);
    }
  }
  float* Cz = g.C + (size_t)z * g.M * g.ldc;
#pragma unroll
  for (int j = 0; j < 4; j++) {
    int c = col0 + n0 + j * 16 + lr;
    if (c >= g.N) continue;
    float bz = (g.bias && z == 0) ? g.bias[c] : 0.f;
#pragma unroll
    for (int i = 0; i < 4; i++) {
      int rbase = row0 + m0 + i * 16 + lk * 4;
#pragma unroll
      for (int r = 0; r < 4; r++) {
        int rr = rbase + r;
        float v = acc[i][j][r] + bz;
        if (g.cmode == 0) Cz[(size_t)rr * g.ldc + c] = v;
        else if (g.cmode == 1) ((_Float16*)g.C)[(size_t)rr * g.ldc + c] = (_Float16)v;
        else ((_Float16*)g.C)[(size_t)c * g.ldc + rr] = (_Float16)v;
      }
    }
  }
}

// ============================ L2: dependent prep + gemms ====================

__global__ __launch_bounds__(256) void k_prep_b(
    const float* __restrict__ Mb, const float* __restrict__ cbf,
    const float* __restrict__ Wlin, const float* __restrict__ blin,
    const float* __restrict__ fcw, const float* __restrict__ OWa,
    _Float16* __restrict__ SWa, float* __restrict__ cba,
    _Float16* __restrict__ Fa,
    GemmJob j1, GemmJob j2, GemmJob j3)
{
  int b = blockIdx.x, tid = threadIdx.x;
  if (b < 780) {   // build_SW
    int ci = b / 260, bx = b % 260;
    int lyr = (ci == 2) ? 1 : 0;
    int ul  = (ci == 0) ? 1 : 0;
    const float* M2 = Mb + (size_t)lyr * 2 * 32768;
    const float* c2 = cbf + (size_t)lyr * 512;
    _Float16* SW = SWa + (size_t)ci * 520 * 128;
    float* cb = cba + (size_t)ci * 520;
    int idx = bx * 256 + tid;
    int urow = idx / 128, s = idx % 128;
    int h = urow / 260, u = urow % 260;
    const float* M = M2 + (size_t)h * 32768;
    const float* c = c2 + h * 256;
    float val = 0.f, cbv = 0.f;
    if (u < 128) {
      if (ul) {
        for (int cc = 0; cc < 128; cc++) {
          float w = Wlin[cc * 128 + u];
          val += w * M[cc * 128 + s];
          cbv += w * c[cc];
        }
      } else { val = M[u * 128 + s]; cbv = c[u]; }
    } else if (u < 256) {
      val = M[u * 128 + s]; cbv = c[u];
    } else if (u == 256) {
      if (ul) {
        for (int cc = 0; cc < 128; cc++) {
          float w = blin[cc];
          val += w * M[cc * 128 + s];
          cbv += w * c[cc];
        }
      }
    }
    SW[(size_t)urow * 128 + s] = (_Float16)val;
    if (s == 0) cb[urow] = cbv;
    return;
  }
  b -= 780;
  if (b < 1560) {  // build_F
    int yy = b / 260, bx = b % 260;
    int ci = yy >> 1, h = yy & 1;
    int lyr = (ci == 2) ? 1 : 0;
    int idx = bx * 256 + tid;
    int p = idx / 260, u = idx % 260;
    const float* fw = fcw + (size_t)lyr * 65536 + (size_t)p * 256 + h * 128;
    const float* ow = OWa + (size_t)ci * 2 * 128 * 260 + (size_t)h * 128 * 260;
    float s = 0.f;
    for (int d = 0; d < 128; d++) s += fw[d] * ow[(size_t)d * 260 + u];
    Fa[(size_t)ci * 256 * 520 + (size_t)p * 520 + h * 260 + u] = (_Float16)s;
    return;
  }
  b -= 1560;
  if (b < j1.nblk) { gemm128_body(b, j1); return; }
  b -= j1.nblk;
  if (b < j2.nblk) { gemm128_body(b, j2); return; }
  b -= j2.nblk;
  if (b < j3.nblk) { gemm128_body(b, j3); return; }
}

// ---- U-GEMM body: A [M][128] f32 resident in LDS, loops 5 col-tiles ----

struct UJob {
  const float* A; const _Float16* B; const float* bias; _Float16* C;
  int nblk;   // M/128
};

__device__ __forceinline__ void ugemm_body(int lb, const UJob& g) {
  __shared__ _Float16 As[128][136];
  __shared__ _Float16 Bs[128][72];
  int tid = threadIdx.x;
  int wv = tid >> 6, lane = tid & 63;
  int wm = wv >> 1, wn = wv & 1;
  int row0 = lb * 128;
  int m0 = wm * 64, n0 = wn * 64;
  int lr = lane & 15, lk = lane >> 4;

  {
    int arow = tid >> 1;
    int acol = (tid & 1) * 64;
    const float* ap = &g.A[(size_t)(row0 + arow) * 128 + acol];
#pragma unroll
    for (int j = 0; j < 16; j++) {
      f4 v = *(const f4*)(ap + j * 4);
      h4 hv = { (_Float16)v.x, (_Float16)v.y, (_Float16)v.z, (_Float16)v.w };
      *(h4*)&As[arow][acol + j * 4] = hv;
    }
  }

  int brow = tid >> 1;
  int bcol = (tid & 1) * 32;
  for (int nt = 0; nt < 5; nt++) {
    int col0 = nt * 128;
    int gbr = col0 + brow;
    bool bvalid = gbr < 520;
    f4 acc[4][4];
#pragma unroll
    for (int i = 0; i < 4; i++)
#pragma unroll
      for (int j = 0; j < 4; j++) acc[i][j] = (f4)0.f;

#pragma unroll
    for (int kk2 = 0; kk2 < 2; kk2++) {
      int k0 = kk2 * 64;
      __syncthreads();
#pragma unroll
      for (int j = 0; j < 8; j++) {
        int ka = k0 + bcol + j * 4;
        h4 hv = (h4)(_Float16)0.f;
        if (bvalid) hv = *(const h4*)&g.B[(size_t)gbr * 128 + ka];
        *(h4*)&Bs[brow][bcol + j * 4] = hv;
      }
      __syncthreads();
#pragma unroll
      for (int kk = 0; kk < 2; kk++) {
        h8 af[4], bf[4];
#pragma unroll
        for (int i = 0; i < 4; i++)
          af[i] = *(h8*)&As[m0 + i * 16 + lr][k0 + kk * 32 + lk * 8];
#pragma unroll
        for (int j = 0; j < 4; j++)
          bf[j] = *(h8*)&Bs[n0 + j * 16 + lr][kk * 32 + lk * 8];
#pragma unroll
        for (int i = 0; i < 4; i++)
#pragma unroll
          for (int j = 0; j < 4; j++)
            acc[i][j] = __builtin_amdgcn_mfma_f32_16x16x32_f16(af[i], bf[j], acc[i][j], 0, 0, 0);
      }
    }
#pragma unroll
    for (int j = 0; j < 4; j++) {
      int c = col0 + n0 + j * 16 + lr;
      if (c >= 520) continue;
      float bz = g.bias[c];
#pragma unroll
      for (int i = 0; i < 4; i++) {
        int rbase = row0 + m0 + i * 16 + lk * 4;
#pragma unroll
        for (int r = 0; r < 4; r++)
          g.C[(size_t)(rbase + r) * 520 + c] = (_Float16)(acc[i][j][r] + bz);
      }
    }
  }
}

__global__ __launch_bounds__(256) void k_gemm_multi(
    GemmJob ja, GemmJob jb, GemmJob jc, const float* lacc, float* finout)
{
  int b = blockIdx.x;
  if (b < ja.nblk) { gemm128_body(b, ja); return; }
  b -= ja.nblk;
  if (b < jb.nblk) { gemm128_body(b, jb); return; }
  b -= jb.nblk;
  if (b < jc.nblk) { gemm128_body(b, jc); return; }
  if (finout && threadIdx.x == 0)
    finout[0] = lacc[0] * (1.0f / (4096.0f * 4096.0f));
}

__global__ __launch_bounds__(256) void k_l3(
    UJob ua, GemmJob jb, GemmJob jc)
{
  int b = blockIdx.x;
  if (b < ua.nblk) { ugemm_body(b, ua); return; }
  b -= ua.nblk;
  if (b < jb.nblk) { gemm128_body(b, jb); return; }
  b -= jb.nblk;
  if (b < jc.nblk) { gemm128_body(b, jc); return; }
}

// ================ score/softmax/aggregate (+ zcomb) dispatcher ==============

struct ScoreJob {
  _Float16* UY; const float* feat; const float* tsrc; const float* tngh;
  const int* idx; int rows;
};

__device__ void score_body(int row, const ScoreJob& J,
                           const float* __restrict__ freq,
                           const float* __restrict__ phase)
{
  __shared__ _Float16 fsh[20][136];
  __shared__ _Float16 tesh[20][136];
  __shared__ _Float16 ush[544];
  __shared__ float fq[128], ph[128];
  __shared__ float ssh[2][20];
  __shared__ float ash[2][20];
  __shared__ float dtsh[20];
  __shared__ int   msh[20];
  int tid = threadIdx.x;
  _Float16* UY = J.UY;

  if (tid < 20) {
    dtsh[tid] = J.tsrc[row] - J.tngh[(size_t)row * 20 + tid];
    msh[tid] = (J.idx[(size_t)row * 20 + tid] == 0);
  }
  if (tid >= 128 && tid < 256) { fq[tid - 128] = freq[tid - 128]; ph[tid - 128] = phase[tid - 128]; }
  if (tid < 130) {
    h4 v = *(const h4*)&UY[(size_t)row * 520 + tid * 4];
    int p4 = (tid < 65) ? tid : tid + 1;
    *(h4*)&ush[p4 * 4] = v;
  }
  const float4* fg = (const float4*)(J.feat + (size_t)row * 2560);
  for (int i = tid; i < 640; i += 256) {
    int j = i >> 5, c4 = i & 31;
    float4 v = fg[i];
    h4 hv = { (_Float16)v.x, (_Float16)v.y, (_Float16)v.z, (_Float16)v.w };
    *(h4*)&fsh[j][c4 * 4] = hv;
  }
  __syncthreads();
  for (int i = tid; i < 2560; i += 256) {
    int j = i >> 7, t = i & 127;
    tesh[j][t] = (_Float16)__cosf(dtsh[j] * fq[t] + ph[t]);
  }
  __syncthreads();

  int g = tid >> 4, li = tid & 15;
#pragma unroll
  for (int it = 0; it < 3; it++) {
    int t = it * 16 + g;
    int valid = (t < 40);
    int h = valid ? (t / 20) : 0;
    int j = valid ? (t % 20) : 0;
    float part = 0.f;
    if (valid) {
      const _Float16* xp = (li < 8) ? &fsh[j][li * 16] : &tesh[j][(li - 8) * 16];
      const _Float16* up = &ush[h * 264 + li * 16];
#pragma unroll
      for (int e = 0; e < 8; e++) {
        h2 a = *(const h2*)(xp + e * 2);
        h2 b2 = *(const h2*)(up + e * 2);
        part = __builtin_amdgcn_fdot2(a, b2, part, false);
      }
    }
    for (int m = 8; m; m >>= 1) part += __shfl_xor(part, m, 16);
    if (valid && li == 0) ssh[h][j] = part + (float)ush[h * 264 + 256];
  }
  __syncthreads();

  if (tid < 64) {
    int head = tid >> 5, l2 = tid & 31;
    const float scale = 0.08838834764831845f; // 1/sqrt(128)
    float s = (l2 < 20) ? (msh[l2] ? -1e10f : ssh[head][l2] * scale) : -3.0e38f;
    float mx = s;
    for (int m = 16; m; m >>= 1) mx = fmaxf(mx, __shfl_xor(mx, m, 32));
    float e = (l2 < 20) ? __expf(s - mx) : 0.f;
    float sum = e;
    for (int m = 16; m; m >>= 1) sum += __shfl_xor(sum, m, 32);
    if (l2 < 20) ash[head][l2] = e / sum;
  }
  __syncthreads();

  {
    int p = tid;
    const _Float16* colp = (p < 128) ? &fsh[0][p] : &tesh[0][p - 128];
    float a0 = 0.f, a1 = 0.f;
#pragma unroll 5
    for (int j = 0; j < 20; j++) {
      float x = (float)colp[j * 136];
      a0 += ash[0][j] * x;
      a1 += ash[1][j] * x;
    }
    UY[(size_t)row * 520 + p] = (_Float16)a0;
    UY[(size_t)row * 520 + 260 + p] = (_Float16)a1;
  }
  if (tid < 8) {
    int p = (tid < 4) ? (256 + tid) : (512 + tid);
    _Float16 v = (_Float16)((tid == 0 || tid == 4) ? 1.f : 0.f);
    UY[(size_t)row * 520 + p] = v;
  }
}

__global__ __launch_bounds__(256, 8) void k_score_multi(
    ScoreJob ja, ScoreJob jb, const float* __restrict__ freq,
    const float* __restrict__ phase,
    const float* __restrict__ zp, _Float16* __restrict__ zh, int nzb)
{
  int b = blockIdx.x;
  if (b < ja.rows) { score_body(b, ja, freq, phase); return; }
  b -= ja.rows;
  if (b < jb.rows) { score_body(b, jb, freq, phase); return; }
  b -= jb.rows;
  if (b < nzb) {
    int i = b * 256 + threadIdx.x;
    const f4* zp4 = (const f4*)zp;
    f4 s = (f4)0.f;
#pragma unroll
    for (int p = 0; p < 8; p++) {
      f4 v = zp4[(size_t)p * 131072 + i];
      s.x += v.x; s.y += v.y; s.z += v.z; s.w += v.w;
    }
    h4 o = { (_Float16)s.x, (_Float16)s.y, (_Float16)s.z, (_Float16)s.w };
    ((h4*)zh)[i] = o;
  }
}

// ============ tail (P-GEMM + LN + MergeLayer) + MFMA-loss dispatcher ========
// LDS diet: one PsBuf holds P (stride 264) during P/m1 phases, then H
// (stride 136) after the post-m1 barrier. src half of m1's A-operand is read
// directly from global f32 (+cvt) instead of a staged Ss tile.

struct TailJob {
  const _Float16* U; const _Float16* F; const float* fcb; const float* srcv;
  const float* lng; const float* lnb;
  const _Float16* m1w; const float* m1b;
  const _Float16* m2w; const float* m2b;
  float* outp; int nblk;
};

__device__ void tail_body(int blk, const TailJob& J, const float* __restrict__ te0)
{
  __shared__ _Float16 PsBuf[64 * 264];
  __shared__ float redS[64][4], redQ[64][4];
  __shared__ float mrow[64], rrow[64];
  int tid = threadIdx.x;
  int wv = tid >> 6, lane = tid & 63;
  int lr = lane & 15, lk = lane >> 4;
  int row0 = blk * 64;
  int n0 = wv * 64;

  // phase 1: P-GEMM (64x256, K=520), fragments direct from global (L2)
  f4 acc[4][4];
#pragma unroll
  for (int i = 0; i < 4; i++)
#pragma unroll
    for (int j = 0; j < 4; j++) acc[i][j] = (f4)0.f;
  for (int kt = 0; kt < 17; kt++) {
    int kb = kt * 32 + lk * 8;
    bool ok = (kb + 8 <= 520);
    h8 af[4], bf[4];
#pragma unroll
    for (int i = 0; i < 4; i++)
      af[i] = ok ? *(const h8*)&J.U[(size_t)(row0 + i * 16 + lr) * 520 + kb]
                 : (h8)(_Float16)0.f;
#pragma unroll
    for (int j = 0; j < 4; j++)
      bf[j] = ok ? *(const h8*)&J.F[(size_t)(n0 + j * 16 + lr) * 520 + kb]
                 : (h8)(_Float16)0.f;
#pragma unroll
    for (int i = 0; i < 4; i++)
#pragma unroll
      for (int j = 0; j < 4; j++)
        acc[i][j] = __builtin_amdgcn_mfma_f32_16x16x32_f16(af[i], bf[j], acc[i][j], 0, 0, 0);
  }

  // epilogue: + fcb + q, row-reduce for LN
#pragma unroll
  for (int i = 0; i < 4; i++) {
#pragma unroll
    for (int r = 0; r < 4; r++) {
      int row_l = i * 16 + lk * 4 + r;
      float rs = 0.f, rq = 0.f;
#pragma unroll
      for (int j = 0; j < 4; j++) {
        int c = n0 + j * 16 + lr;
        float q = (c < 128) ? J.srcv[(size_t)(row0 + row_l) * 128 + c] : te0[c - 128];
        float v = acc[i][j][r] + J.fcb[c] + q;
        acc[i][j][r] = v;
        rs += v; rq += v * v;
      }
      for (int m = 8; m; m >>= 1) {
        rs += __shfl_xor(rs, m, 16);
        rq += __shfl_xor(rq, m, 16);
      }
      if (lr == 0) { redS[row_l][wv] = rs; redQ[row_l][wv] = rq; }
    }
  }
  __syncthreads();
  if (tid < 64) {
    float s4 = redS[tid][0] + redS[tid][1] + redS[tid][2] + redS[tid][3];
    float q4 = redQ[tid][0] + redQ[tid][1] + redQ[tid][2] + redQ[tid][3];
    float mean = s4 * (1.0f / 256.0f);
    float var = q4 * (1.0f / 256.0f) - mean * mean;
    mrow[tid] = mean;
    rrow[tid] = rsqrtf(var + 1e-5f);
  }
  __syncthreads();
#pragma unroll
  for (int i = 0; i < 4; i++) {
#pragma unroll
    for (int r = 0; r < 4; r++) {
      int row_l = i * 16 + lk * 4 + r;
      float mean = mrow[row_l], rstd = rrow[row_l];
#pragma unroll
      for (int j = 0; j < 4; j++) {
        int c = n0 + j * 16 + lr;
        PsBuf[row_l * 264 + c] =
            (_Float16)((acc[i][j][r] - mean) * rstd * J.lng[c] + J.lnb[c]);
      }
    }
  }
  __syncthreads();

  // phase 2: m1 (64x128, K=384: [P | src]); src half direct from global
  int wm = wv >> 1, wn = wv & 1;
  f4 a2[2][4];
#pragma unroll
  for (int i = 0; i < 2; i++)
#pragma unroll
    for (int j = 0; j < 4; j++) a2[i][j] = (f4)0.f;
  for (int kk = 0; kk < 12; kk++) {
    int kb = kk * 32 + lk * 8;
    h8 af[2], bf[4];
#pragma unroll
    for (int i = 0; i < 2; i++) {
      int rl = wm * 32 + i * 16 + lr;
      if (kb < 256) {
        af[i] = *(const h8*)&PsBuf[rl * 264 + kb];
      } else {
        const float* sp = &J.srcv[(size_t)(row0 + rl) * 128 + (kb - 256)];
        f4 v0 = *(const f4*)sp;
        f4 v1 = *(const f4*)(sp + 4);
        af[i] = h8{ (_Float16)v0.x, (_Float16)v0.y, (_Float16)v0.z, (_Float16)v0.w,
                    (_Float16)v1.x, (_Float16)v1.y, (_Float16)v1.z, (_Float16)v1.w };
      }
    }
#pragma unroll
    for (int j = 0; j < 4; j++)
      bf[j] = *(const h8*)&J.m1w[(size_t)(wn * 64 + j * 16 + lr) * 384 + kb];
#pragma unroll
    for (int i = 0; i < 2; i++)
#pragma unroll
      for (int j = 0; j < 4; j++)
        a2[i][j] = __builtin_amdgcn_mfma_f32_16x16x32_f16(af[i], bf[j], a2[i][j], 0, 0, 0);
  }
  __syncthreads();   // everyone done reading P before H overlays it
#pragma unroll
  for (int i = 0; i < 2; i++) {
#pragma unroll
    for (int j = 0; j < 4; j++) {
      int c = wn * 64 + j * 16 + lr;
      float bz = J.m1b[c];
#pragma unroll
      for (int r = 0; r < 4; r++) {
        float v = a2[i][j][r] + bz;
        if (v < 0.f) v = 0.f;
        PsBuf[(wm * 32 + i * 16 + lk * 4 + r) * 136 + c] = (_Float16)v;   // H
      }
    }
  }
  __syncthreads();

  // phase 3: m2 (64x128, K=128)
  f4 a3[2][4];
#pragma unroll
  for (int i = 0; i < 2; i++)
#pragma unroll
    for (int j = 0; j < 4; j++) a3[i][j] = (f4)0.f;
#pragma unroll
  for (int kk = 0; kk < 4; kk++) {
    int kb = kk * 32 + lk * 8;
    h8 af[2], bf[4];
#pragma unroll
    for (int i = 0; i < 2; i++)
      af[i] = *(const h8*)&PsBuf[(wm * 32 + i * 16 + lr) * 136 + kb];
#pragma unroll
    for (int j = 0; j < 4; j++)
      bf[j] = *(const h8*)&J.m2w[(size_t)(wn * 64 + j * 16 + lr) * 128 + kb];
#pragma unroll
    for (int i = 0; i < 2; i++)
#pragma unroll
      for (int j = 0; j < 4; j++)
        a3[i][j] = __builtin_amdgcn_mfma_f32_16x16x32_f16(af[i], bf[j], a3[i][j], 0, 0, 0);
  }
#pragma unroll
  for (int j = 0; j < 4; j++) {
    int c = wn * 64 + j * 16 + lr;
    float bz = J.m2b[c];
#pragma unroll
    for (int i = 0; i < 2; i++) {
#pragma unroll
      for (int r = 0; r < 4; r++) {
        int rl = wm * 32 + i * 16 + lk * 4 + r;
        J.outp[(size_t)(row0 + rl) * 128 + c] = a3[i][j][r] + bz;
      }
    }
  }
}

__device__ void loss_body(int b, const _Float16* __restrict__ z,
                          const float* __restrict__ adj, float* __restrict__ acc)
{
  int bi = b & 31, bj = b >> 5;
  int tid = threadIdx.x;
  int wv = tid >> 6, lane = tid & 63;
  int wm = wv >> 1, wn = wv & 1;
  int lr = lane & 15, lk = lane >> 4;
  int row0 = bi * 128 + wm * 64;
  int col0 = bj * 128 + wn * 64;

  f4 accf[4][4];
#pragma unroll
  for (int i = 0; i < 4; i++)
#pragma unroll
    for (int j = 0; j < 4; j++) accf[i][j] = (f4)0.f;

#pragma unroll
  for (int kk = 0; kk < 4; kk++) {
    int ko = kk * 32 + lk * 8;
    h8 af[4], bf[4];
#pragma unroll
    for (int i = 0; i < 4; i++)
      af[i] = *(const h8*)&z[(size_t)(row0 + i * 16 + lr) * 128 + ko];
#pragma unroll
    for (int j = 0; j < 4; j++)
      bf[j] = *(const h8*)&z[(size_t)(col0 + j * 16 + lr) * 128 + ko];
#pragma unroll
    for (int i = 0; i < 4; i++)
#pragma unroll
      for (int j = 0; j < 4; j++)
        accf[i][j] = __builtin_amdgcn_mfma_f32_16x16x32_f16(af[i], bf[j], accf[i][j], 0, 0, 0);
  }

  float lsum = 0.f;
#pragma unroll
  for (int i = 0; i < 4; i++) {
    int rbase = row0 + i * 16 + lk * 4;
#pragma unroll
    for (int r = 0; r < 4; r++) {
      const float* arow = adj + (size_t)(rbase + r) * 4096;
#pragma unroll
      for (int j = 0; j < 4; j++) {
        float x = accf[i][j][r];
        float s = 1.0f / (1.0f + __expf(-x));
        float d = arow[col0 + j * 16 + lr] - s;
        lsum += d * d;
      }
    }
  }
  for (int m = 32; m; m >>= 1) lsum += __shfl_xor(lsum, m, 64);
  if (lane == 0) atomicAdd(acc, lsum);
}

__global__ __launch_bounds__(256, 3) void k_tail_loss(
    TailJob ja, TailJob jb, const float* __restrict__ te0,
    const _Float16* __restrict__ z, const float* __restrict__ adj,
    float* __restrict__ lacc, int nloss)
{
  int b = blockIdx.x;
  if (b < ja.nblk) { tail_body(b, ja, te0); return; }
  b -= ja.nblk;
  if (b < jb.nblk) { tail_body(b, jb, te0); return; }
  b -= jb.nblk;
  if (b < nloss) loss_body(b, z, adj, lacc);
}

// ---------------------------------------------------------------------------

extern "C" void kernel_launch(void* const* d_in, const int* in_sizes, int n_in,
                              void* d_out, int out_size, void* d_ws, size_t ws_size,
                              hipStream_t stream) {
  const float* src_feat  = (const float*)d_in[0];
  const float* src_t     = (const float*)d_in[1];
  const int*   ngh1_idx  = (const int*)d_in[2];
  const float* ngh1_t    = (const float*)d_in[3];
  const float* ngh1_feat = (const float*)d_in[4];
  const int*   ngh2_idx  = (const int*)d_in[5];
  const float* ngh2_t    = (const float*)d_in[6];
  const float* ngh2_feat = (const float*)d_in[7];
  const float* ae_x      = (const float*)d_in[8];
  const float* ae_adj    = (const float*)d_in[9];
  const float* W_lin     = (const float*)d_in[10];
  const float* b_lin     = (const float*)d_in[11];
  const float* freq      = (const float*)d_in[12];
  const float* phase     = (const float*)d_in[13];
  const float* wq        = (const float*)d_in[14];
  const float* wk        = (const float*)d_in[15];
  const float* wvp       = (const float*)d_in[16];
  const float* fcw       = (const float*)d_in[17];
  const float* fcb       = (const float*)d_in[18];
  const float* lng       = (const float*)d_in[19];
  const float* lnb       = (const float*)d_in[20];
  const float* m1w       = (const float*)d_in[21];
  const float* m1b       = (const float*)d_in[22];
  const float* m2w       = (const float*)d_in[23];
  const float* m2b       = (const float*)d_in[24];
  const float* W_gc      = (const float*)d_in[25];
  const float* b_gc      = (const float*)d_in[26];
  float* out = (float*)d_out;

  const int NB = 2048, NA = 40960;

  char* w = (char*)d_ws;
  size_t off = 0;
  auto alloc = [&](size_t bytes) -> void* {
    void* p = (void*)(w + off);
    off += (bytes + 255) & ~(size_t)255;
    return p;
  };
  float* te0    = (float*)alloc(128 * 4);
  float* linS   = (float*)alloc((size_t)NB * 128 * 4);
  float* lin1   = (float*)alloc((size_t)NA * 128 * 4);
  float* src_l1 = (float*)alloc((size_t)NB * 128 * 4);
  float* ngh_l1 = (float*)alloc((size_t)NA * 128 * 4);
  float* Mb     = (float*)alloc((size_t)4 * 32768 * 4);
  float* cbf    = (float*)alloc(4 * 256 * 4);
  _Float16* SWh = (_Float16*)alloc((size_t)3 * 520 * 128 * 2);
  float* cbU    = (float*)alloc(3 * 520 * 4);
  float* OW     = (float*)alloc((size_t)3 * 2 * 128 * 260 * 4);
  _Float16* Fh  = (_Float16*)alloc((size_t)3 * 256 * 520 * 2);
  _Float16* Wlinh = (_Float16*)alloc(16384 * 2);
  _Float16* m1wh  = (_Float16*)alloc((size_t)2 * 128 * 384 * 2);
  _Float16* m2wh  = (_Float16*)alloc((size_t)2 * 128 * 128 * 2);
  _Float16* WgcTh = (_Float16*)alloc(16384 * 2);
  _Float16* xwTh  = (_Float16*)alloc((size_t)4096 * 128 * 2);
  float* zpart    = (float*)alloc((size_t)8 * 4096 * 128 * 4);
  _Float16* zh    = (_Float16*)alloc((size_t)4096 * 128 * 2);
  float* lacc     = (float*)alloc(256);
  _Float16* UbufA = (_Float16*)alloc((size_t)NA * 520 * 2);
  _Float16* UbufB = (_Float16*)alloc((size_t)NB * 520 * 2);
  _Float16* UbufC = (_Float16*)alloc((size_t)NB * 520 * 2);

  // L1: independent prep
  k_prep_a<<<1936, 256, 0, stream>>>(phase, wq, wk, wvp, W_lin, b_lin, m1w, m2w,
                                     W_gc, te0, cbf, Mb, OW, Wlinh, m1wh, m2wh,
                                     WgcTh, lacc);

  // L2: dependent prep + {linS, lin1, xwT}
  GemmJob jLinS = { src_feat,  Wlinh, b_lin,   linS,         128, 128, 128,
                    2048, 128, 128, 0, 128, 16, 1, 16 };
  GemmJob jLin1 = { ngh1_feat, Wlinh, b_lin,   lin1,         128, 128, 128,
                    40960, 128, 128, 0, 128, 320, 1, 320 };
  GemmJob jXwT  = { ae_x,      WgcTh, nullptr, (float*)xwTh, 128, 128, 4096,
                    4096, 128, 128, 2, 128, 32, 1, 32 };
  k_prep_b<<<2708, 256, 0, stream>>>(Mb, cbf, W_lin, b_lin, fcw, OW, SWh, cbU,
                                     Fh, jLinS, jLin1, jXwT);

  // L3: {U-A (A-resident), U-B, zb split-K=8}
  UJob uA = { lin1, SWh, cbU, UbufA, 320 };
  GemmJob jUB = { linS, SWh + 520 * 128,  cbU + 520, (float*)UbufB, 128, 128, 520,
                  2048, 520, 128, 1, 128, 16, 5, 80 };
  GemmJob jZB = { ae_adj, xwTh, b_gc, zpart, 4096, 4096, 128,
                  4096, 128, 4096, 0, 512, 32, 1, 256 };
  k_l3<<<320 + 80 + 256, 256, 0, stream>>>(uA, jUB, jZB);

  // L4: {score-A, score-B, zcomb}
  ScoreJob sA = { UbufA, ngh2_feat, ngh1_t, ngh2_t, ngh2_idx, NA };
  ScoreJob sB = { UbufB, lin1,      src_t,  ngh1_t, ngh1_idx, NB };
  k_score_multi<<<NA + NB + 512, 256, 0, stream>>>(sA, sB, freq, phase,
                                                   zpart, zh, 512);

  // L5: {tail-A, tail-B, loss}
  TailJob tA = { UbufA, Fh,             fcb, lin1, lng, lnb,
                 m1wh, m1b, m2wh, m2b, ngh_l1, NA / 64 };
  TailJob tB = { UbufB, Fh + 256 * 520, fcb, linS, lng, lnb,
                 m1wh, m1b, m2wh, m2b, src_l1, NB / 64 };
  k_tail_loss<<<NA / 64 + NB / 64 + 1024, 256, 0, stream>>>(
      tA, tB, te0, zh, ae_adj, lacc, 1024);

  // L6: {U-C, final loss write}
  GemmJob j0 = {};
  GemmJob jUC = { src_l1, SWh + 2 * 520 * 128, cbU + 2 * 520, (float*)UbufC,
                  128, 128, 520, 2048, 520, 128, 1, 128, 16, 5, 80 };
  k_gemm_multi<<<81, 256, 0, stream>>>(jUC, j0, j0, lacc, out + (size_t)NB * 128);

  // L7: {score-C}
  ScoreJob sC = { UbufC, ngh_l1, src_t, ngh1_t, ngh1_idx, NB };
  ScoreJob s0 = {};
  k_score_multi<<<NB, 256, 0, stream>>>(sC, s0, freq, phase, nullptr, nullptr, 0);

  // L8: {tail-C} -> d_out
  TailJob tC = { UbufC, Fh + 2 * 256 * 520, fcb + 256, src_l1, lng + 256, lnb + 256,
                 m1wh + 128 * 384, m1b + 128, m2wh + 128 * 128, m2b + 128,
                 out, NB / 64 };
  TailJob t0 = {};
  k_tail_loss<<<NB / 64, 256, 0, stream>>>(tC, t0, te0, nullptr, nullptr,
                                           nullptr, 0);
}

// Round 11
// 479.704 us; speedup vs baseline: 1.0081x; 1.0081x over previous
//
#include <hip/hip_runtime.h>
#include <math.h>

// ---------------------------------------------------------------------------
// TGAT classifier. Algebraic folding (score/aggregate in input space,
// wq/wk/wv/W_lin/fc_w folded into SW/F), f16 MFMA everywhere.
// Round 11: exact round-9 structure (9 launches, 464us) + ONE delta:
//   tail LDS diet (PsBuf overlay; src half of m1 direct from global;
//   launch_bounds(256,3)) -> tail occupancy 2 -> 3 blocks/CU.
// ---------------------------------------------------------------------------

typedef _Float16 h2 __attribute__((ext_vector_type(2)));
typedef _Float16 h4 __attribute__((ext_vector_type(4)));
typedef _Float16 h8 __attribute__((ext_vector_type(8)));
typedef float f4 __attribute__((ext_vector_type(4)));

// ============================ L1: independent prep ==========================

__global__ __launch_bounds__(256) void k_prep_a(
    const float* __restrict__ phase, const float* __restrict__ wq,
    const float* __restrict__ wk, const float* __restrict__ wvw,
    const float* __restrict__ Wlin, const float* __restrict__ blin,
    const float* __restrict__ m1w, const float* __restrict__ m2w,
    const float* __restrict__ Wgc,
    float* __restrict__ te0, float* __restrict__ cbf, float* __restrict__ Mb,
    float* __restrict__ OWa,
    _Float16* __restrict__ Wlinh, _Float16* __restrict__ m1wh,
    _Float16* __restrict__ m2wh, _Float16* __restrict__ WgcTh,
    float* __restrict__ lacc)
{
  __shared__ float te[128];
  __shared__ float bqv[128];
  int b = blockIdx.x, tid = threadIdx.x;

  if (b < 4) {
    int l = b >> 1, h = b & 1;
    if (tid < 128) {
      te[tid] = cosf(phase[tid]);
      if (b == 0) te0[tid] = te[tid];
    }
    __syncthreads();
    if (tid < 128) {
      const float* wr = wq + ((size_t)(l * 256 + h * 128 + tid)) * 256 + 128;
      float s = 0.f;
      for (int k = 0; k < 128; k++) s += wr[k] * te[k];
      bqv[tid] = s;
    }
    __syncthreads();
    {
      const float* wkb = wk + (size_t)l * 65536 + (size_t)h * 32768;
      float s = 0.f;
      for (int d = 0; d < 128; d++) s += wkb[(size_t)d * 256 + tid] * bqv[d];
      cbf[(l * 2 + h) * 256 + tid] = s;
    }
    return;
  }
  b -= 4;
  if (b < 512) {   // prepM
    int lh = b >> 7, bx = b & 127;
    int l = lh >> 1, h = lh & 1;
    int idx = bx * 256 + tid;
    int e = idx >> 7, s = idx & 127;
    const float* wkb = wk + (size_t)l * 65536 + (size_t)h * 32768;
    const float* wqb = wq + (size_t)l * 65536 + (size_t)h * 32768;
    float acc = 0.f;
    for (int d = 0; d < 128; d++)
      acc += wkb[(size_t)d * 256 + e] * wqb[(size_t)d * 256 + s];
    Mb[(size_t)lh * 32768 + idx] = acc;
    return;
  }
  b -= 512;
  if (b < 780) {   // build_OW
    int ci = b / 260, bx = b % 260;
    int lyr = (ci == 2) ? 1 : 0;
    int ul  = (ci == 0) ? 1 : 0;
    float* OW = OWa + (size_t)ci * 2 * 128 * 260;
    const float* wvl = wvw + (size_t)lyr * 65536;
    int idx = bx * 256 + tid;
    int u = idx % 260; int d = (idx / 260) % 128; int h = idx / (260 * 128);
    const float* wr = wvl + (size_t)(h * 128 + d) * 256;
    float val = 0.f;
    if (u < 128) {
      if (ul) { for (int cc = 0; cc < 128; cc++) val += wr[cc] * Wlin[cc * 128 + u]; }
      else val = wr[u];
    } else if (u < 256) {
      val = wr[u];
    } else if (u == 256) {
      if (ul) { for (int cc = 0; cc < 128; cc++) val += wr[cc] * blin[cc]; }
    }
    OW[idx] = val;
    return;
  }
  b -= 780;
  {  // converts + lacc zero (640 blocks)
    int idx = b * 256 + tid;
    if (idx == 0) lacc[0] = 0.f;
    int i = idx;
    if (i < 16384) { Wlinh[i] = (_Float16)Wlin[i]; return; }
    i -= 16384;
    if (i < 98304) { m1wh[i] = (_Float16)m1w[i]; return; }
    i -= 98304;
    if (i < 32768) { m2wh[i] = (_Float16)m2w[i]; return; }
    i -= 32768;
    {
      int c = i >> 7, r = i & 127;
      WgcTh[i] = (_Float16)Wgc[(size_t)r * 128 + c];
    }
  }
}

// ============================ L2: dependent prep ============================

__global__ __launch_bounds__(256) void k_prep_b(
    const float* __restrict__ Mb, const float* __restrict__ cbf,
    const float* __restrict__ Wlin, const float* __restrict__ blin,
    const float* __restrict__ fcw, const float* __restrict__ OWa,
    _Float16* __restrict__ SWa, float* __restrict__ cba,
    _Float16* __restrict__ Fa)
{
  int b = blockIdx.x, tid = threadIdx.x;
  if (b < 780) {   // build_SW
    int ci = b / 260, bx = b % 260;
    int lyr = (ci == 2) ? 1 : 0;
    int ul  = (ci == 0) ? 1 : 0;
    const float* M2 = Mb + (size_t)lyr * 2 * 32768;
    const float* c2 = cbf + (size_t)lyr * 512;
    _Float16* SW = SWa + (size_t)ci * 520 * 128;
    float* cb = cba + (size_t)ci * 520;
    int idx = bx * 256 + tid;
    int urow = idx / 128, s = idx % 128;
    int h = urow / 260, u = urow % 260;
    const float* M = M2 + (size_t)h * 32768;
    const float* c = c2 + h * 256;
    float val = 0.f, cbv = 0.f;
    if (u < 128) {
      if (ul) {
        for (int cc = 0; cc < 128; cc++) {
          float w = Wlin[cc * 128 + u];
          val += w * M[cc * 128 + s];
          cbv += w * c[cc];
        }
      } else { val = M[u * 128 + s]; cbv = c[u]; }
    } else if (u < 256) {
      val = M[u * 128 + s]; cbv = c[u];
    } else if (u == 256) {
      if (ul) {
        for (int cc = 0; cc < 128; cc++) {
          float w = blin[cc];
          val += w * M[cc * 128 + s];
          cbv += w * c[cc];
        }
      }
    }
    SW[(size_t)urow * 128 + s] = (_Float16)val;
    if (s == 0) cb[urow] = cbv;
    return;
  }
  b -= 780;
  {  // build_F: 1560 blocks
    int yy = b / 260, bx = b % 260;
    int ci = yy >> 1, h = yy & 1;
    int lyr = (ci == 2) ? 1 : 0;
    int idx = bx * 256 + tid;
    int p = idx / 260, u = idx % 260;
    const float* fw = fcw + (size_t)lyr * 65536 + (size_t)p * 256 + h * 128;
    const float* ow = OWa + (size_t)ci * 2 * 128 * 260 + (size_t)h * 128 * 260;
    float s = 0.f;
    for (int d = 0; d < 128; d++) s += fw[d] * ow[(size_t)d * 260 + u];
    Fa[(size_t)ci * 256 * 520 + (size_t)p * 520 + h * 260 + u] = (_Float16)s;
  }
}

// ===================== shared f16 MFMA GEMM body ============================

struct GemmJob {
  const float* A; const _Float16* B; const float* bias; float* C;
  int lda, ldb, ldc, M, N, K, cmode, klen, gx, gy, nblk;
};

__device__ __forceinline__ void gemm128_body(int lb, const GemmJob& g) {
  __shared__ _Float16 As[128][72];
  __shared__ _Float16 Bs[128][72];
  int bx = lb % g.gx;
  int rest = lb / g.gx;
  int by = rest % g.gy;
  int z = rest / g.gy;

  int tid = threadIdx.x;
  int wv = tid >> 6, lane = tid & 63;
  int wm = wv >> 1, wn = wv & 1;
  int row0 = bx * 128, col0 = by * 128;
  int m0 = wm * 64, n0 = wn * 64;
  int lr = lane & 15, lk = lane >> 4;
  int kbeg = z * g.klen;
  int kend = kbeg + g.klen; if (kend > g.K) kend = g.K;

  f4 acc[4][4];
#pragma unroll
  for (int i = 0; i < 4; i++)
#pragma unroll
    for (int j = 0; j < 4; j++) acc[i][j] = (f4)0.f;

  int arow = tid >> 1;
  int acol = (tid & 1) * 32;
  int gar = row0 + arow;
  int gbr = col0 + arow;
  bool bvalid = gbr < g.N;

  for (int k0 = kbeg; k0 < kend; k0 += 64) {
    __syncthreads();
#pragma unroll
    for (int j = 0; j < 8; j++) {
      int ka = k0 + acol + j * 4;
      f4 v = (f4)0.f;
      if (ka < g.K) v = *(const f4*)&g.A[(size_t)gar * g.lda + ka];
      h4 hv = { (_Float16)v.x, (_Float16)v.y, (_Float16)v.z, (_Float16)v.w };
      *(h4*)&As[arow][acol + j * 4] = hv;
    }
#pragma unroll
    for (int j = 0; j < 8; j++) {
      int ka = k0 + acol + j * 4;
      h4 hv = (h4)(_Float16)0.f;
      if (bvalid && ka < g.K) hv = *(const h4*)&g.B[(size_t)gbr * g.ldb + ka];
      *(h4*)&Bs[arow][acol + j * 4] = hv;
    }
    __syncthreads();
#pragma unroll
    for (int kk = 0; kk < 2; kk++) {
      h8 af[4], bf[4];
#pragma unroll
      for (int i = 0; i < 4; i++)
        af[i] = *(h8*)&As[m0 + i * 16 + lr][kk * 32 + lk * 8];
#pragma unroll
      for (int j = 0; j < 4; j++)
        bf[j] = *(h8*)&Bs[n0 + j * 16 + lr][kk * 32 + lk * 8];
#pragma unroll
      for (int i = 0; i < 4; i++)
#pragma unroll
        for (int j = 0; j < 4; j++)
          acc[i][j] = __builtin_amdgcn_mfma_f32_16x16x32_f16(af[i], bf[j], acc[i][j], 0, 0, 0);
    }
  }
  float* Cz = g.C + (size_t)z * g.M * g.ldc;
#pragma unroll
  for (int j = 0; j < 4; j++) {
    int c = col0 + n0 + j * 16 + lr;
    if (c >= g.N) continue;
    float bz = (g.bias && z == 0) ? g.bias[c] : 0.f;
#pragma unroll
    for (int i = 0; i < 4; i++) {
      int rbase = row0 + m0 + i * 16 + lk * 4;
#pragma unroll
      for (int r = 0; r < 4; r++) {
        int rr = rbase + r;
        float v = acc[i][j][r] + bz;
        if (g.cmode == 0) Cz[(size_t)rr * g.ldc + c] = v;
        else if (g.cmode == 1) ((_Float16*)g.C)[(size_t)rr * g.ldc + c] = (_Float16)v;
        else ((_Float16*)g.C)[(size_t)c * g.ldc + rr] = (_Float16)v;
      }
    }
  }
}

// ---- U-GEMM body: A [M][128] f32 resident in LDS, loops 5 col-tiles ----

struct UJob {
  const float* A; const _Float16* B; const float* bias; _Float16* C;
  int nblk;   // M/128
};

__device__ __forceinline__ void ugemm_body(int lb, const UJob& g) {
  __shared__ _Float16 As[128][136];
  __shared__ _Float16 Bs[128][72];
  int tid = threadIdx.x;
  int wv = tid >> 6, lane = tid & 63;
  int wm = wv >> 1, wn = wv & 1;
  int row0 = lb * 128;
  int m0 = wm * 64, n0 = wn * 64;
  int lr = lane & 15, lk = lane >> 4;

  {
    int arow = tid >> 1;
    int acol = (tid & 1) * 64;
    const float* ap = &g.A[(size_t)(row0 + arow) * 128 + acol];
#pragma unroll
    for (int j = 0; j < 16; j++) {
      f4 v = *(const f4*)(ap + j * 4);
      h4 hv = { (_Float16)v.x, (_Float16)v.y, (_Float16)v.z, (_Float16)v.w };
      *(h4*)&As[arow][acol + j * 4] = hv;
    }
  }

  int brow = tid >> 1;
  int bcol = (tid & 1) * 32;
  for (int nt = 0; nt < 5; nt++) {
    int col0 = nt * 128;
    int gbr = col0 + brow;
    bool bvalid = gbr < 520;
    f4 acc[4][4];
#pragma unroll
    for (int i = 0; i < 4; i++)
#pragma unroll
      for (int j = 0; j < 4; j++) acc[i][j] = (f4)0.f;

#pragma unroll
    for (int kk2 = 0; kk2 < 2; kk2++) {
      int k0 = kk2 * 64;
      __syncthreads();
#pragma unroll
      for (int j = 0; j < 8; j++) {
        int ka = k0 + bcol + j * 4;
        h4 hv = (h4)(_Float16)0.f;
        if (bvalid) hv = *(const h4*)&g.B[(size_t)gbr * 128 + ka];
        *(h4*)&Bs[brow][bcol + j * 4] = hv;
      }
      __syncthreads();
#pragma unroll
      for (int kk = 0; kk < 2; kk++) {
        h8 af[4], bf[4];
#pragma unroll
        for (int i = 0; i < 4; i++)
          af[i] = *(h8*)&As[m0 + i * 16 + lr][k0 + kk * 32 + lk * 8];
#pragma unroll
        for (int j = 0; j < 4; j++)
          bf[j] = *(h8*)&Bs[n0 + j * 16 + lr][kk * 32 + lk * 8];
#pragma unroll
        for (int i = 0; i < 4; i++)
#pragma unroll
          for (int j = 0; j < 4; j++)
            acc[i][j] = __builtin_amdgcn_mfma_f32_16x16x32_f16(af[i], bf[j], acc[i][j], 0, 0, 0);
      }
    }
#pragma unroll
    for (int j = 0; j < 4; j++) {
      int c = col0 + n0 + j * 16 + lr;
      if (c >= 520) continue;
      float bz = g.bias[c];
#pragma unroll
      for (int i = 0; i < 4; i++) {
        int rbase = row0 + m0 + i * 16 + lk * 4;
#pragma unroll
        for (int r = 0; r < 4; r++)
          g.C[(size_t)(rbase + r) * 520 + c] = (_Float16)(acc[i][j][r] + bz);
      }
    }
  }
}

__global__ __launch_bounds__(256) void k_gemm_multi(
    GemmJob ja, GemmJob jb, GemmJob jc, const float* lacc, float* finout)
{
  int b = blockIdx.x;
  if (b < ja.nblk) { gemm128_body(b, ja); return; }
  b -= ja.nblk;
  if (b < jb.nblk) { gemm128_body(b, jb); return; }
  b -= jb.nblk;
  if (b < jc.nblk) { gemm128_body(b, jc); return; }
  if (finout && threadIdx.x == 0)
    finout[0] = lacc[0] * (1.0f / (4096.0f * 4096.0f));
}

__global__ __launch_bounds__(256) void k_l3(
    UJob ua, GemmJob jb, GemmJob jc)
{
  int b = blockIdx.x;
  if (b < ua.nblk) { ugemm_body(b, ua); return; }
  b -= ua.nblk;
  if (b < jb.nblk) { gemm128_body(b, jb); return; }
  b -= jb.nblk;
  if (b < jc.nblk) { gemm128_body(b, jc); return; }
}

// ================ score/softmax/aggregate (+ zcomb) dispatcher ==============

struct ScoreJob {
  _Float16* UY; const float* feat; const float* tsrc; const float* tngh;
  const int* idx; int rows;
};

__device__ void score_body(int row, const ScoreJob& J,
                           const float* __restrict__ freq,
                           const float* __restrict__ phase)
{
  __shared__ _Float16 fsh[20][136];
  __shared__ _Float16 tesh[20][136];
  __shared__ _Float16 ush[544];
  __shared__ float fq[128], ph[128];
  __shared__ float ssh[2][20];
  __shared__ float ash[2][20];
  __shared__ float dtsh[20];
  __shared__ int   msh[20];
  int tid = threadIdx.x;
  _Float16* UY = J.UY;

  if (tid < 20) {
    dtsh[tid] = J.tsrc[row] - J.tngh[(size_t)row * 20 + tid];
    msh[tid] = (J.idx[(size_t)row * 20 + tid] == 0);
  }
  if (tid >= 128 && tid < 256) { fq[tid - 128] = freq[tid - 128]; ph[tid - 128] = phase[tid - 128]; }
  if (tid < 130) {
    h4 v = *(const h4*)&UY[(size_t)row * 520 + tid * 4];
    int p4 = (tid < 65) ? tid : tid + 1;
    *(h4*)&ush[p4 * 4] = v;
  }
  const float4* fg = (const float4*)(J.feat + (size_t)row * 2560);
  for (int i = tid; i < 640; i += 256) {
    int j = i >> 5, c4 = i & 31;
    float4 v = fg[i];
    h4 hv = { (_Float16)v.x, (_Float16)v.y, (_Float16)v.z, (_Float16)v.w };
    *(h4*)&fsh[j][c4 * 4] = hv;
  }
  __syncthreads();
  for (int i = tid; i < 2560; i += 256) {
    int j = i >> 7, t = i & 127;
    tesh[j][t] = (_Float16)__cosf(dtsh[j] * fq[t] + ph[t]);
  }
  __syncthreads();

  int g = tid >> 4, li = tid & 15;
#pragma unroll
  for (int it = 0; it < 3; it++) {
    int t = it * 16 + g;
    int valid = (t < 40);
    int h = valid ? (t / 20) : 0;
    int j = valid ? (t % 20) : 0;
    float part = 0.f;
    if (valid) {
      const _Float16* xp = (li < 8) ? &fsh[j][li * 16] : &tesh[j][(li - 8) * 16];
      const _Float16* up = &ush[h * 264 + li * 16];
#pragma unroll
      for (int e = 0; e < 8; e++) {
        h2 a = *(const h2*)(xp + e * 2);
        h2 b2 = *(const h2*)(up + e * 2);
        part = __builtin_amdgcn_fdot2(a, b2, part, false);
      }
    }
    for (int m = 8; m; m >>= 1) part += __shfl_xor(part, m, 16);
    if (valid && li == 0) ssh[h][j] = part + (float)ush[h * 264 + 256];
  }
  __syncthreads();

  if (tid < 64) {
    int head = tid >> 5, l2 = tid & 31;
    const float scale = 0.08838834764831845f; // 1/sqrt(128)
    float s = (l2 < 20) ? (msh[l2] ? -1e10f : ssh[head][l2] * scale) : -3.0e38f;
    float mx = s;
    for (int m = 16; m; m >>= 1) mx = fmaxf(mx, __shfl_xor(mx, m, 32));
    float e = (l2 < 20) ? __expf(s - mx) : 0.f;
    float sum = e;
    for (int m = 16; m; m >>= 1) sum += __shfl_xor(sum, m, 32);
    if (l2 < 20) ash[head][l2] = e / sum;
  }
  __syncthreads();

  {
    int p = tid;
    const _Float16* colp = (p < 128) ? &fsh[0][p] : &tesh[0][p - 128];
    float a0 = 0.f, a1 = 0.f;
#pragma unroll 5
    for (int j = 0; j < 20; j++) {
      float x = (float)colp[j * 136];
      a0 += ash[0][j] * x;
      a1 += ash[1][j] * x;
    }
    UY[(size_t)row * 520 + p] = (_Float16)a0;
    UY[(size_t)row * 520 + 260 + p] = (_Float16)a1;
  }
  if (tid < 8) {
    int p = (tid < 4) ? (256 + tid) : (512 + tid);
    _Float16 v = (_Float16)((tid == 0 || tid == 4) ? 1.f : 0.f);
    UY[(size_t)row * 520 + p] = v;
  }
}

__global__ __launch_bounds__(256, 8) void k_score_multi(
    ScoreJob ja, ScoreJob jb, const float* __restrict__ freq,
    const float* __restrict__ phase,
    const float* __restrict__ zp, _Float16* __restrict__ zh, int nzb)
{
  int b = blockIdx.x;
  if (b < ja.rows) { score_body(b, ja, freq, phase); return; }
  b -= ja.rows;
  if (b < jb.rows) { score_body(b, jb, freq, phase); return; }
  b -= jb.rows;
  if (b < nzb) {
    int i = b * 256 + threadIdx.x;
    const f4* zp4 = (const f4*)zp;
    f4 s = (f4)0.f;
#pragma unroll
    for (int p = 0; p < 8; p++) {
      f4 v = zp4[(size_t)p * 131072 + i];
      s.x += v.x; s.y += v.y; s.z += v.z; s.w += v.w;
    }
    h4 o = { (_Float16)s.x, (_Float16)s.y, (_Float16)s.z, (_Float16)s.w };
    ((h4*)zh)[i] = o;
  }
}

// ============ tail (P-GEMM + LN + MergeLayer) + MFMA-loss dispatcher ========
// LDS diet: one PsBuf holds P (stride 264) during P/m1 phases, then H
// (stride 136) after the post-m1 barrier. src half of m1's A-operand read
// directly from global f32 (+cvt). 36.1 KB -> 3 blocks/CU.

struct TailJob {
  const _Float16* U; const _Float16* F; const float* fcb; const float* srcv;
  const float* lng; const float* lnb;
  const _Float16* m1w; const float* m1b;
  const _Float16* m2w; const float* m2b;
  float* outp; int nblk;
};

__device__ void tail_body(int blk, const TailJob& J, const float* __restrict__ te0)
{
  __shared__ _Float16 PsBuf[64 * 264];
  __shared__ float redS[64][4], redQ[64][4];
  __shared__ float mrow[64], rrow[64];
  int tid = threadIdx.x;
  int wv = tid >> 6, lane = tid & 63;
  int lr = lane & 15, lk = lane >> 4;
  int row0 = blk * 64;
  int n0 = wv * 64;

  // phase 1: P-GEMM (64x256, K=520), fragments direct from global (L2)
  f4 acc[4][4];
#pragma unroll
  for (int i = 0; i < 4; i++)
#pragma unroll
    for (int j = 0; j < 4; j++) acc[i][j] = (f4)0.f;
  for (int kt = 0; kt < 17; kt++) {
    int kb = kt * 32 + lk * 8;
    bool ok = (kb + 8 <= 520);
    h8 af[4], bf[4];
#pragma unroll
    for (int i = 0; i < 4; i++)
      af[i] = ok ? *(const h8*)&J.U[(size_t)(row0 + i * 16 + lr) * 520 + kb]
                 : (h8)(_Float16)0.f;
#pragma unroll
    for (int j = 0; j < 4; j++)
      bf[j] = ok ? *(const h8*)&J.F[(size_t)(n0 + j * 16 + lr) * 520 + kb]
                 : (h8)(_Float16)0.f;
#pragma unroll
    for (int i = 0; i < 4; i++)
#pragma unroll
      for (int j = 0; j < 4; j++)
        acc[i][j] = __builtin_amdgcn_mfma_f32_16x16x32_f16(af[i], bf[j], acc[i][j], 0, 0, 0);
  }

  // epilogue: + fcb + q, row-reduce for LN
#pragma unroll
  for (int i = 0; i < 4; i++) {
#pragma unroll
    for (int r = 0; r < 4; r++) {
      int row_l = i * 16 + lk * 4 + r;
      float rs = 0.f, rq = 0.f;
#pragma unroll
      for (int j = 0; j < 4; j++) {
        int c = n0 + j * 16 + lr;
        float q = (c < 128) ? J.srcv[(size_t)(row0 + row_l) * 128 + c] : te0[c - 128];
        float v = acc[i][j][r] + J.fcb[c] + q;
        acc[i][j][r] = v;
        rs += v; rq += v * v;
      }
      for (int m = 8; m; m >>= 1) {
        rs += __shfl_xor(rs, m, 16);
        rq += __shfl_xor(rq, m, 16);
      }
      if (lr == 0) { redS[row_l][wv] = rs; redQ[row_l][wv] = rq; }
    }
  }
  __syncthreads();
  if (tid < 64) {
    float s4 = redS[tid][0] + redS[tid][1] + redS[tid][2] + redS[tid][3];
    float q4 = redQ[tid][0] + redQ[tid][1] + redQ[tid][2] + redQ[tid][3];
    float mean = s4 * (1.0f / 256.0f);
    float var = q4 * (1.0f / 256.0f) - mean * mean;
    mrow[tid] = mean;
    rrow[tid] = rsqrtf(var + 1e-5f);
  }
  __syncthreads();
#pragma unroll
  for (int i = 0; i < 4; i++) {
#pragma unroll
    for (int r = 0; r < 4; r++) {
      int row_l = i * 16 + lk * 4 + r;
      float mean = mrow[row_l], rstd = rrow[row_l];
#pragma unroll
      for (int j = 0; j < 4; j++) {
        int c = n0 + j * 16 + lr;
        PsBuf[row_l * 264 + c] =
            (_Float16)((acc[i][j][r] - mean) * rstd * J.lng[c] + J.lnb[c]);
      }
    }
  }
  __syncthreads();

  // phase 2: m1 (64x128, K=384: [P | src]); src half direct from global
  int wm = wv >> 1, wn = wv & 1;
  f4 a2[2][4];
#pragma unroll
  for (int i = 0; i < 2; i++)
#pragma unroll
    for (int j = 0; j < 4; j++) a2[i][j] = (f4)0.f;
  for (int kk = 0; kk < 12; kk++) {
    int kb = kk * 32 + lk * 8;
    h8 af[2], bf[4];
#pragma unroll
    for (int i = 0; i < 2; i++) {
      int rl = wm * 32 + i * 16 + lr;
      if (kb < 256) {
        af[i] = *(const h8*)&PsBuf[rl * 264 + kb];
      } else {
        const float* sp = &J.srcv[(size_t)(row0 + rl) * 128 + (kb - 256)];
        f4 v0 = *(const f4*)sp;
        f4 v1 = *(const f4*)(sp + 4);
        af[i] = h8{ (_Float16)v0.x, (_Float16)v0.y, (_Float16)v0.z, (_Float16)v0.w,
                    (_Float16)v1.x, (_Float16)v1.y, (_Float16)v1.z, (_Float16)v1.w };
      }
    }
#pragma unroll
    for (int j = 0; j < 4; j++)
      bf[j] = *(const h8*)&J.m1w[(size_t)(wn * 64 + j * 16 + lr) * 384 + kb];
#pragma unroll
    for (int i = 0; i < 2; i++)
#pragma unroll
      for (int j = 0; j < 4; j++)
        a2[i][j] = __builtin_amdgcn_mfma_f32_16x16x32_f16(af[i], bf[j], a2[i][j], 0, 0, 0);
  }
  __syncthreads();   // everyone done reading P before H overlays it
#pragma unroll
  for (int i = 0; i < 2; i++) {
#pragma unroll
    for (int j = 0; j < 4; j++) {
      int c = wn * 64 + j * 16 + lr;
      float bz = J.m1b[c];
#pragma unroll
      for (int r = 0; r < 4; r++) {
        float v = a2[i][j][r] + bz;
        if (v < 0.f) v = 0.f;
        PsBuf[(wm * 32 + i * 16 + lk * 4 + r) * 136 + c] = (_Float16)v;   // H
      }
    }
  }
  __syncthreads();

  // phase 3: m2 (64x128, K=128)
  f4 a3[2][4];
#pragma unroll
  for (int i = 0; i < 2; i++)
#pragma unroll
    for (int j = 0; j < 4; j++) a3[i][j] = (f4)0.f;
#pragma unroll
  for (int kk = 0; kk < 4; kk++) {
    int kb = kk * 32 + lk * 8;
    h8 af[2], bf[4];
#pragma unroll
    for (int i = 0; i < 2; i++)
      af[i] = *(const h8*)&PsBuf[(wm * 32 + i * 16 + lr) * 136 + kb];
#pragma unroll
    for (int j = 0; j < 4; j++)
      bf[j] = *(const h8*)&J.m2w[(size_t)(wn * 64 + j * 16 + lr) * 128 + kb];
#pragma unroll
    for (int i = 0; i < 2; i++)
#pragma unroll
      for (int j = 0; j < 4; j++)
        a3[i][j] = __builtin_amdgcn_mfma_f32_16x16x32_f16(af[i], bf[j], a3[i][j], 0, 0, 0);
  }
#pragma unroll
  for (int j = 0; j < 4; j++) {
    int c = wn * 64 + j * 16 + lr;
    float bz = J.m2b[c];
#pragma unroll
    for (int i = 0; i < 2; i++) {
#pragma unroll
      for (int r = 0; r < 4; r++) {
        int rl = wm * 32 + i * 16 + lk * 4 + r;
        J.outp[(size_t)(row0 + rl) * 128 + c] = a3[i][j][r] + bz;
      }
    }
  }
}

__device__ void loss_body(int b, const _Float16* __restrict__ z,
                          const float* __restrict__ adj, float* __restrict__ acc)
{
  int bi = b & 31, bj = b >> 5;
  int tid = threadIdx.x;
  int wv = tid >> 6, lane = tid & 63;
  int wm = wv >> 1, wn = wv & 1;
  int lr = lane & 15, lk = lane >> 4;
  int row0 = bi * 128 + wm * 64;
  int col0 = bj * 128 + wn * 64;

  f4 accf[4][4];
#pragma unroll
  for (int i = 0; i < 4; i++)
#pragma unroll
    for (int j = 0; j < 4; j++) accf[i][j] = (f4)0.f;

#pragma unroll
  for (int kk = 0; kk < 4; kk++) {
    int ko = kk * 32 + lk * 8;
    h8 af[4], bf[4];
#pragma unroll
    for (int i = 0; i < 4; i++)
      af[i] = *(const h8*)&z[(size_t)(row0 + i * 16 + lr) * 128 + ko];
#pragma unroll
    for (int j = 0; j < 4; j++)
      bf[j] = *(const h8*)&z[(size_t)(col0 + j * 16 + lr) * 128 + ko];
#pragma unroll
    for (int i = 0; i < 4; i++)
#pragma unroll
      for (int j = 0; j < 4; j++)
        accf[i][j] = __builtin_amdgcn_mfma_f32_16x16x32_f16(af[i], bf[j], accf[i][j], 0, 0, 0);
  }

  float lsum = 0.f;
#pragma unroll
  for (int i = 0; i < 4; i++) {
    int rbase = row0 + i * 16 + lk * 4;
#pragma unroll
    for (int r = 0; r < 4; r++) {
      const float* arow = adj + (size_t)(rbase + r) * 4096;
#pragma unroll
      for (int j = 0; j < 4; j++) {
        float x = accf[i][j][r];
        float s = 1.0f / (1.0f + __expf(-x));
        float d = arow[col0 + j * 16 + lr] - s;
        lsum += d * d;
      }
    }
  }
  for (int m = 32; m; m >>= 1) lsum += __shfl_xor(lsum, m, 64);
  if (lane == 0) atomicAdd(acc, lsum);
}

__global__ __launch_bounds__(256, 3) void k_tail_loss(
    TailJob ja, TailJob jb, const float* __restrict__ te0,
    const _Float16* __restrict__ z, const float* __restrict__ adj,
    float* __restrict__ lacc, int nloss)
{
  int b = blockIdx.x;
  if (b < ja.nblk) { tail_body(b, ja, te0); return; }
  b -= ja.nblk;
  if (b < jb.nblk) { tail_body(b, jb, te0); return; }
  b -= jb.nblk;
  if (b < nloss) loss_body(b, z, adj, lacc);
}

// ---------------------------------------------------------------------------

extern "C" void kernel_launch(void* const* d_in, const int* in_sizes, int n_in,
                              void* d_out, int out_size, void* d_ws, size_t ws_size,
                              hipStream_t stream) {
  const float* src_feat  = (const float*)d_in[0];
  const float* src_t     = (const float*)d_in[1];
  const int*   ngh1_idx  = (const int*)d_in[2];
  const float* ngh1_t    = (const float*)d_in[3];
  const float* ngh1_feat = (const float*)d_in[4];
  const int*   ngh2_idx  = (const int*)d_in[5];
  const float* ngh2_t    = (const float*)d_in[6];
  const float* ngh2_feat = (const float*)d_in[7];
  const float* ae_x      = (const float*)d_in[8];
  const float* ae_adj    = (const float*)d_in[9];
  const float* W_lin     = (const float*)d_in[10];
  const float* b_lin     = (const float*)d_in[11];
  const float* freq      = (const float*)d_in[12];
  const float* phase     = (const float*)d_in[13];
  const float* wq        = (const float*)d_in[14];
  const float* wk        = (const float*)d_in[15];
  const float* wvp       = (const float*)d_in[16];
  const float* fcw       = (const float*)d_in[17];
  const float* fcb       = (const float*)d_in[18];
  const float* lng       = (const float*)d_in[19];
  const float* lnb       = (const float*)d_in[20];
  const float* m1w       = (const float*)d_in[21];
  const float* m1b       = (const float*)d_in[22];
  const float* m2w       = (const float*)d_in[23];
  const float* m2b       = (const float*)d_in[24];
  const float* W_gc      = (const float*)d_in[25];
  const float* b_gc      = (const float*)d_in[26];
  float* out = (float*)d_out;

  const int NB = 2048, NA = 40960;

  char* w = (char*)d_ws;
  size_t off = 0;
  auto alloc = [&](size_t bytes) -> void* {
    void* p = (void*)(w + off);
    off += (bytes + 255) & ~(size_t)255;
    return p;
  };
  float* te0    = (float*)alloc(128 * 4);
  float* linS   = (float*)alloc((size_t)NB * 128 * 4);
  float* lin1   = (float*)alloc((size_t)NA * 128 * 4);
  float* src_l1 = (float*)alloc((size_t)NB * 128 * 4);
  float* ngh_l1 = (float*)alloc((size_t)NA * 128 * 4);
  float* Mb     = (float*)alloc((size_t)4 * 32768 * 4);
  float* cbf    = (float*)alloc(4 * 256 * 4);
  _Float16* SWh = (_Float16*)alloc((size_t)3 * 520 * 128 * 2);
  float* cbU    = (float*)alloc(3 * 520 * 4);
  float* OW     = (float*)alloc((size_t)3 * 2 * 128 * 260 * 4);
  _Float16* Fh  = (_Float16*)alloc((size_t)3 * 256 * 520 * 2);
  _Float16* Wlinh = (_Float16*)alloc(16384 * 2);
  _Float16* m1wh  = (_Float16*)alloc((size_t)2 * 128 * 384 * 2);
  _Float16* m2wh  = (_Float16*)alloc((size_t)2 * 128 * 128 * 2);
  _Float16* WgcTh = (_Float16*)alloc(16384 * 2);
  _Float16* xwTh  = (_Float16*)alloc((size_t)4096 * 128 * 2);
  float* zpart    = (float*)alloc((size_t)8 * 4096 * 128 * 4);
  _Float16* zh    = (_Float16*)alloc((size_t)4096 * 128 * 2);
  float* lacc     = (float*)alloc(256);
  _Float16* UbufA = (_Float16*)alloc((size_t)NA * 520 * 2);
  _Float16* UbufB = (_Float16*)alloc((size_t)NB * 520 * 2);
  _Float16* UbufC = (_Float16*)alloc((size_t)NB * 520 * 2);

  // L1: independent prep
  k_prep_a<<<1936, 256, 0, stream>>>(phase, wq, wk, wvp, W_lin, b_lin, m1w, m2w,
                                     W_gc, te0, cbf, Mb, OW, Wlinh, m1wh, m2wh,
                                     WgcTh, lacc);
  // L2: dependent prep
  k_prep_b<<<2340, 256, 0, stream>>>(Mb, cbf, W_lin, b_lin, fcw, OW, SWh, cbU, Fh);

  GemmJob j0 = {};

  // L3: {linS, lin1, xwT}
  GemmJob jLinS = { src_feat,  Wlinh, b_lin,   linS,         128, 128, 128,
                    2048, 128, 128, 0, 128, 16, 1, 16 };
  GemmJob jLin1 = { ngh1_feat, Wlinh, b_lin,   lin1,         128, 128, 128,
                    40960, 128, 128, 0, 128, 320, 1, 320 };
  GemmJob jXwT  = { ae_x,      WgcTh, nullptr, (float*)xwTh, 128, 128, 4096,
                    4096, 128, 128, 2, 128, 32, 1, 32 };
  k_gemm_multi<<<368, 256, 0, stream>>>(jLinS, jLin1, jXwT, nullptr, nullptr);

  // L4: {U-A (A-resident), U-B, zb split-K=8}
  UJob uA = { lin1, SWh, cbU, UbufA, 320 };
  GemmJob jUB = { linS, SWh + 520 * 128,  cbU + 520, (float*)UbufB, 128, 128, 520,
                  2048, 520, 128, 1, 128, 16, 5, 80 };
  GemmJob jZB = { ae_adj, xwTh, b_gc, zpart, 4096, 4096, 128,
                  4096, 128, 4096, 0, 512, 32, 1, 256 };
  k_l3<<<320 + 80 + 256, 256, 0, stream>>>(uA, jUB, jZB);

  // L5: {score-A, score-B, zcomb}
  ScoreJob sA = { UbufA, ngh2_feat, ngh1_t, ngh2_t, ngh2_idx, NA };
  ScoreJob sB = { UbufB, lin1,      src_t,  ngh1_t, ngh1_idx, NB };
  k_score_multi<<<NA + NB + 512, 256, 0, stream>>>(sA, sB, freq, phase,
                                                   zpart, zh, 512);

  // L6: {tail-A, tail-B, loss}
  TailJob tA = { UbufA, Fh,             fcb, lin1, lng, lnb,
                 m1wh, m1b, m2wh, m2b, ngh_l1, NA / 64 };
  TailJob tB = { UbufB, Fh + 256 * 520, fcb, linS, lng, lnb,
                 m1wh, m1b, m2wh, m2b, src_l1, NB / 64 };
  k_tail_loss<<<NA / 64 + NB / 64 + 1024, 256, 0, stream>>>(
      tA, tB, te0, zh, ae_adj, lacc, 1024);

  // L7: {U-C, final loss write}
  GemmJob jUC = { src_l1, SWh + 2 * 520 * 128, cbU + 2 * 520, (float*)UbufC,
                  128, 128, 520, 2048, 520, 128, 1, 128, 16, 5, 80 };
  k_gemm_multi<<<81, 256, 0, stream>>>(jUC, j0, j0, lacc, out + (size_t)NB * 128);

  // L8: {score-C}
  ScoreJob sC = { UbufC, ngh_l1, src_t, ngh1_t, ngh1_idx, NB };
  ScoreJob s0 = {};
  k_score_multi<<<NB, 256, 0, stream>>>(sC, s0, freq, phase, nullptr, nullptr, 0);

  // L9: {tail-C} -> d_out
  TailJob tC = { UbufC, Fh + 2 * 256 * 520, fcb + 256, src_l1, lng + 256, lnb + 256,
                 m1wh + 128 * 384, m1b + 128, m2wh + 128 * 128, m2b + 128,
                 out, NB / 64 };
  TailJob t0 = {};
  k_tail_loss<<<NB / 64, 256, 0, stream>>>(tC, t0, te0, nullptr, nullptr,
                                           nullptr, 0);
}

// Round 12
// 463.880 us; speedup vs baseline: 1.0425x; 1.0341x over previous
//
#include <hip/hip_runtime.h>
#include <math.h>

// ---------------------------------------------------------------------------
// TGAT classifier. Algebraic folding (score/aggregate in input space,
// wq/wk/wv/W_lin/fc_w folded into SW/F), f16 MFMA everywhere.
// Round 12: pure revert to measured-best round-9 kernel (464us).
//   9 launches; ugemm_body (A-resident) for U-A; score with fq/ph LDS
//   staging; original tail (Ps+Ss staged).
// ---------------------------------------------------------------------------

typedef _Float16 h2 __attribute__((ext_vector_type(2)));
typedef _Float16 h4 __attribute__((ext_vector_type(4)));
typedef _Float16 h8 __attribute__((ext_vector_type(8)));
typedef float f4 __attribute__((ext_vector_type(4)));

// ============================ L1: independent prep ==========================

__global__ __launch_bounds__(256) void k_prep_a(
    const float* __restrict__ phase, const float* __restrict__ wq,
    const float* __restrict__ wk, const float* __restrict__ wvw,
    const float* __restrict__ Wlin, const float* __restrict__ blin,
    const float* __restrict__ m1w, const float* __restrict__ m2w,
    const float* __restrict__ Wgc,
    float* __restrict__ te0, float* __restrict__ cbf, float* __restrict__ Mb,
    float* __restrict__ OWa,
    _Float16* __restrict__ Wlinh, _Float16* __restrict__ m1wh,
    _Float16* __restrict__ m2wh, _Float16* __restrict__ WgcTh,
    float* __restrict__ lacc)
{
  __shared__ float te[128];
  __shared__ float bqv[128];
  int b = blockIdx.x, tid = threadIdx.x;

  if (b < 4) {
    int l = b >> 1, h = b & 1;
    if (tid < 128) {
      te[tid] = cosf(phase[tid]);
      if (b == 0) te0[tid] = te[tid];
    }
    __syncthreads();
    if (tid < 128) {
      const float* wr = wq + ((size_t)(l * 256 + h * 128 + tid)) * 256 + 128;
      float s = 0.f;
      for (int k = 0; k < 128; k++) s += wr[k] * te[k];
      bqv[tid] = s;
    }
    __syncthreads();
    {
      const float* wkb = wk + (size_t)l * 65536 + (size_t)h * 32768;
      float s = 0.f;
      for (int d = 0; d < 128; d++) s += wkb[(size_t)d * 256 + tid] * bqv[d];
      cbf[(l * 2 + h) * 256 + tid] = s;
    }
    return;
  }
  b -= 4;
  if (b < 512) {   // prepM
    int lh = b >> 7, bx = b & 127;
    int l = lh >> 1, h = lh & 1;
    int idx = bx * 256 + tid;
    int e = idx >> 7, s = idx & 127;
    const float* wkb = wk + (size_t)l * 65536 + (size_t)h * 32768;
    const float* wqb = wq + (size_t)l * 65536 + (size_t)h * 32768;
    float acc = 0.f;
    for (int d = 0; d < 128; d++)
      acc += wkb[(size_t)d * 256 + e] * wqb[(size_t)d * 256 + s];
    Mb[(size_t)lh * 32768 + idx] = acc;
    return;
  }
  b -= 512;
  if (b < 780) {   // build_OW
    int ci = b / 260, bx = b % 260;
    int lyr = (ci == 2) ? 1 : 0;
    int ul  = (ci == 0) ? 1 : 0;
    float* OW = OWa + (size_t)ci * 2 * 128 * 260;
    const float* wvl = wvw + (size_t)lyr * 65536;
    int idx = bx * 256 + tid;
    int u = idx % 260; int d = (idx / 260) % 128; int h = idx / (260 * 128);
    const float* wr = wvl + (size_t)(h * 128 + d) * 256;
    float val = 0.f;
    if (u < 128) {
      if (ul) { for (int cc = 0; cc < 128; cc++) val += wr[cc] * Wlin[cc * 128 + u]; }
      else val = wr[u];
    } else if (u < 256) {
      val = wr[u];
    } else if (u == 256) {
      if (ul) { for (int cc = 0; cc < 128; cc++) val += wr[cc] * blin[cc]; }
    }
    OW[idx] = val;
    return;
  }
  b -= 780;
  {  // converts + lacc zero (640 blocks)
    int idx = b * 256 + tid;
    if (idx == 0) lacc[0] = 0.f;
    int i = idx;
    if (i < 16384) { Wlinh[i] = (_Float16)Wlin[i]; return; }
    i -= 16384;
    if (i < 98304) { m1wh[i] = (_Float16)m1w[i]; return; }
    i -= 98304;
    if (i < 32768) { m2wh[i] = (_Float16)m2w[i]; return; }
    i -= 32768;
    {
      int c = i >> 7, r = i & 127;
      WgcTh[i] = (_Float16)Wgc[(size_t)r * 128 + c];
    }
  }
}

// ============================ L2: dependent prep ============================

__global__ __launch_bounds__(256) void k_prep_b(
    const float* __restrict__ Mb, const float* __restrict__ cbf,
    const float* __restrict__ Wlin, const float* __restrict__ blin,
    const float* __restrict__ fcw, const float* __restrict__ OWa,
    _Float16* __restrict__ SWa, float* __restrict__ cba,
    _Float16* __restrict__ Fa)
{
  int b = blockIdx.x, tid = threadIdx.x;
  if (b < 780) {   // build_SW
    int ci = b / 260, bx = b % 260;
    int lyr = (ci == 2) ? 1 : 0;
    int ul  = (ci == 0) ? 1 : 0;
    const float* M2 = Mb + (size_t)lyr * 2 * 32768;
    const float* c2 = cbf + (size_t)lyr * 512;
    _Float16* SW = SWa + (size_t)ci * 520 * 128;
    float* cb = cba + (size_t)ci * 520;
    int idx = bx * 256 + tid;
    int urow = idx / 128, s = idx % 128;
    int h = urow / 260, u = urow % 260;
    const float* M = M2 + (size_t)h * 32768;
    const float* c = c2 + h * 256;
    float val = 0.f, cbv = 0.f;
    if (u < 128) {
      if (ul) {
        for (int cc = 0; cc < 128; cc++) {
          float w = Wlin[cc * 128 + u];
          val += w * M[cc * 128 + s];
          cbv += w * c[cc];
        }
      } else { val = M[u * 128 + s]; cbv = c[u]; }
    } else if (u < 256) {
      val = M[u * 128 + s]; cbv = c[u];
    } else if (u == 256) {
      if (ul) {
        for (int cc = 0; cc < 128; cc++) {
          float w = blin[cc];
          val += w * M[cc * 128 + s];
          cbv += w * c[cc];
        }
      }
    }
    SW[(size_t)urow * 128 + s] = (_Float16)val;
    if (s == 0) cb[urow] = cbv;
    return;
  }
  b -= 780;
  {  // build_F: 1560 blocks
    int yy = b / 260, bx = b % 260;
    int ci = yy >> 1, h = yy & 1;
    int lyr = (ci == 2) ? 1 : 0;
    int idx = bx * 256 + tid;
    int p = idx / 260, u = idx % 260;
    const float* fw = fcw + (size_t)lyr * 65536 + (size_t)p * 256 + h * 128;
    const float* ow = OWa + (size_t)ci * 2 * 128 * 260 + (size_t)h * 128 * 260;
    float s = 0.f;
    for (int d = 0; d < 128; d++) s += fw[d] * ow[(size_t)d * 260 + u];
    Fa[(size_t)ci * 256 * 520 + (size_t)p * 520 + h * 260 + u] = (_Float16)s;
  }
}

// ===================== shared f16 MFMA GEMM body ============================

struct GemmJob {
  const float* A; const _Float16* B; const float* bias; float* C;
  int lda, ldb, ldc, M, N, K, cmode, klen, gx, gy, nblk;
};

__device__ __forceinline__ void gemm128_body(int lb, const GemmJob& g) {
  __shared__ _Float16 As[128][72];
  __shared__ _Float16 Bs[128][72];
  int bx = lb % g.gx;
  int rest = lb / g.gx;
  int by = rest % g.gy;
  int z = rest / g.gy;

  int tid = threadIdx.x;
  int wv = tid >> 6, lane = tid & 63;
  int wm = wv >> 1, wn = wv & 1;
  int row0 = bx * 128, col0 = by * 128;
  int m0 = wm * 64, n0 = wn * 64;
  int lr = lane & 15, lk = lane >> 4;
  int kbeg = z * g.klen;
  int kend = kbeg + g.klen; if (kend > g.K) kend = g.K;

  f4 acc[4][4];
#pragma unroll
  for (int i = 0; i < 4; i++)
#pragma unroll
    for (int j = 0; j < 4; j++) acc[i][j] = (f4)0.f;

  int arow = tid >> 1;
  int acol = (tid & 1) * 32;
  int gar = row0 + arow;
  int gbr = col0 + arow;
  bool bvalid = gbr < g.N;

  for (int k0 = kbeg; k0 < kend; k0 += 64) {
    __syncthreads();
#pragma unroll
    for (int j = 0; j < 8; j++) {
      int ka = k0 + acol + j * 4;
      f4 v = (f4)0.f;
      if (ka < g.K) v = *(const f4*)&g.A[(size_t)gar * g.lda + ka];
      h4 hv = { (_Float16)v.x, (_Float16)v.y, (_Float16)v.z, (_Float16)v.w };
      *(h4*)&As[arow][acol + j * 4] = hv;
    }
#pragma unroll
    for (int j = 0; j < 8; j++) {
      int ka = k0 + acol + j * 4;
      h4 hv = (h4)(_Float16)0.f;
      if (bvalid && ka < g.K) hv = *(const h4*)&g.B[(size_t)gbr * g.ldb + ka];
      *(h4*)&Bs[arow][acol + j * 4] = hv;
    }
    __syncthreads();
#pragma unroll
    for (int kk = 0; kk < 2; kk++) {
      h8 af[4], bf[4];
#pragma unroll
      for (int i = 0; i < 4; i++)
        af[i] = *(h8*)&As[m0 + i * 16 + lr][kk * 32 + lk * 8];
#pragma unroll
      for (int j = 0; j < 4; j++)
        bf[j] = *(h8*)&Bs[n0 + j * 16 + lr][kk * 32 + lk * 8];
#pragma unroll
      for (int i = 0; i < 4; i++)
#pragma unroll
        for (int j = 0; j < 4; j++)
          acc[i][j] = __builtin_amdgcn_mfma_f32_16x16x32_f16(af[i], bf[j], acc[i][j], 0, 0, 0);
    }
  }
  float* Cz = g.C + (size_t)z * g.M * g.ldc;
#pragma unroll
  for (int j = 0; j < 4; j++) {
    int c = col0 + n0 + j * 16 + lr;
    if (c >= g.N) continue;
    float bz = (g.bias && z == 0) ? g.bias[c] : 0.f;
#pragma unroll
    for (int i = 0; i < 4; i++) {
      int rbase = row0 + m0 + i * 16 + lk * 4;
#pragma unroll
      for (int r = 0; r < 4; r++) {
        int rr = rbase + r;
        float v = acc[i][j][r] + bz;
        if (g.cmode == 0) Cz[(size_t)rr * g.ldc + c] = v;
        else if (g.cmode == 1) ((_Float16*)g.C)[(size_t)rr * g.ldc + c] = (_Float16)v;
        else ((_Float16*)g.C)[(size_t)c * g.ldc + rr] = (_Float16)v;
      }
    }
  }
}

// ---- U-GEMM body: A [M][128] f32 resident in LDS, loops 5 col-tiles ----

struct UJob {
  const float* A; const _Float16* B; const float* bias; _Float16* C;
  int nblk;   // M/128
};

__device__ __forceinline__ void ugemm_body(int lb, const UJob& g) {
  __shared__ _Float16 As[128][136];
  __shared__ _Float16 Bs[128][72];
  int tid = threadIdx.x;
  int wv = tid >> 6, lane = tid & 63;
  int wm = wv >> 1, wn = wv & 1;
  int row0 = lb * 128;
  int m0 = wm * 64, n0 = wn * 64;
  int lr = lane & 15, lk = lane >> 4;

  {
    int arow = tid >> 1;
    int acol = (tid & 1) * 64;
    const float* ap = &g.A[(size_t)(row0 + arow) * 128 + acol];
#pragma unroll
    for (int j = 0; j < 16; j++) {
      f4 v = *(const f4*)(ap + j * 4);
      h4 hv = { (_Float16)v.x, (_Float16)v.y, (_Float16)v.z, (_Float16)v.w };
      *(h4*)&As[arow][acol + j * 4] = hv;
    }
  }

  int brow = tid >> 1;
  int bcol = (tid & 1) * 32;
  for (int nt = 0; nt < 5; nt++) {
    int col0 = nt * 128;
    int gbr = col0 + brow;
    bool bvalid = gbr < 520;
    f4 acc[4][4];
#pragma unroll
    for (int i = 0; i < 4; i++)
#pragma unroll
      for (int j = 0; j < 4; j++) acc[i][j] = (f4)0.f;

#pragma unroll
    for (int kk2 = 0; kk2 < 2; kk2++) {
      int k0 = kk2 * 64;
      __syncthreads();
#pragma unroll
      for (int j = 0; j < 8; j++) {
        int ka = k0 + bcol + j * 4;
        h4 hv = (h4)(_Float16)0.f;
        if (bvalid) hv = *(const h4*)&g.B[(size_t)gbr * 128 + ka];
        *(h4*)&Bs[brow][bcol + j * 4] = hv;
      }
      __syncthreads();
#pragma unroll
      for (int kk = 0; kk < 2; kk++) {
        h8 af[4], bf[4];
#pragma unroll
        for (int i = 0; i < 4; i++)
          af[i] = *(h8*)&As[m0 + i * 16 + lr][k0 + kk * 32 + lk * 8];
#pragma unroll
        for (int j = 0; j < 4; j++)
          bf[j] = *(h8*)&Bs[n0 + j * 16 + lr][kk * 32 + lk * 8];
#pragma unroll
        for (int i = 0; i < 4; i++)
#pragma unroll
          for (int j = 0; j < 4; j++)
            acc[i][j] = __builtin_amdgcn_mfma_f32_16x16x32_f16(af[i], bf[j], acc[i][j], 0, 0, 0);
      }
    }
#pragma unroll
    for (int j = 0; j < 4; j++) {
      int c = col0 + n0 + j * 16 + lr;
      if (c >= 520) continue;
      float bz = g.bias[c];
#pragma unroll
      for (int i = 0; i < 4; i++) {
        int rbase = row0 + m0 + i * 16 + lk * 4;
#pragma unroll
        for (int r = 0; r < 4; r++)
          g.C[(size_t)(rbase + r) * 520 + c] = (_Float16)(acc[i][j][r] + bz);
      }
    }
  }
}

__global__ __launch_bounds__(256) void k_gemm_multi(
    GemmJob ja, GemmJob jb, GemmJob jc, const float* lacc, float* finout)
{
  int b = blockIdx.x;
  if (b < ja.nblk) { gemm128_body(b, ja); return; }
  b -= ja.nblk;
  if (b < jb.nblk) { gemm128_body(b, jb); return; }
  b -= jb.nblk;
  if (b < jc.nblk) { gemm128_body(b, jc); return; }
  if (finout && threadIdx.x == 0)
    finout[0] = lacc[0] * (1.0f / (4096.0f * 4096.0f));
}

__global__ __launch_bounds__(256) void k_l3(
    UJob ua, GemmJob jb, GemmJob jc)
{
  int b = blockIdx.x;
  if (b < ua.nblk) { ugemm_body(b, ua); return; }
  b -= ua.nblk;
  if (b < jb.nblk) { gemm128_body(b, jb); return; }
  b -= jb.nblk;
  if (b < jc.nblk) { gemm128_body(b, jc); return; }
}

// ================ score/softmax/aggregate (+ zcomb) dispatcher ==============

struct ScoreJob {
  _Float16* UY; const float* feat; const float* tsrc; const float* tngh;
  const int* idx; int rows;
};

__device__ void score_body(int row, const ScoreJob& J,
                           const float* __restrict__ freq,
                           const float* __restrict__ phase)
{
  __shared__ _Float16 fsh[20][136];
  __shared__ _Float16 tesh[20][136];
  __shared__ _Float16 ush[544];
  __shared__ float fq[128], ph[128];
  __shared__ float ssh[2][20];
  __shared__ float ash[2][20];
  __shared__ float dtsh[20];
  __shared__ int   msh[20];
  int tid = threadIdx.x;
  _Float16* UY = J.UY;

  if (tid < 20) {
    dtsh[tid] = J.tsrc[row] - J.tngh[(size_t)row * 20 + tid];
    msh[tid] = (J.idx[(size_t)row * 20 + tid] == 0);
  }
  if (tid >= 128 && tid < 256) { fq[tid - 128] = freq[tid - 128]; ph[tid - 128] = phase[tid - 128]; }
  if (tid < 130) {
    h4 v = *(const h4*)&UY[(size_t)row * 520 + tid * 4];
    int p4 = (tid < 65) ? tid : tid + 1;
    *(h4*)&ush[p4 * 4] = v;
  }
  const float4* fg = (const float4*)(J.feat + (size_t)row * 2560);
  for (int i = tid; i < 640; i += 256) {
    int j = i >> 5, c4 = i & 31;
    float4 v = fg[i];
    h4 hv = { (_Float16)v.x, (_Float16)v.y, (_Float16)v.z, (_Float16)v.w };
    *(h4*)&fsh[j][c4 * 4] = hv;
  }
  __syncthreads();
  for (int i = tid; i < 2560; i += 256) {
    int j = i >> 7, t = i & 127;
    tesh[j][t] = (_Float16)__cosf(dtsh[j] * fq[t] + ph[t]);
  }
  __syncthreads();

  int g = tid >> 4, li = tid & 15;
#pragma unroll
  for (int it = 0; it < 3; it++) {
    int t = it * 16 + g;
    int valid = (t < 40);
    int h = valid ? (t / 20) : 0;
    int j = valid ? (t % 20) : 0;
    float part = 0.f;
    if (valid) {
      const _Float16* xp = (li < 8) ? &fsh[j][li * 16] : &tesh[j][(li - 8) * 16];
      const _Float16* up = &ush[h * 264 + li * 16];
#pragma unroll
      for (int e = 0; e < 8; e++) {
        h2 a = *(const h2*)(xp + e * 2);
        h2 b2 = *(const h2*)(up + e * 2);
        part = __builtin_amdgcn_fdot2(a, b2, part, false);
      }
    }
    for (int m = 8; m; m >>= 1) part += __shfl_xor(part, m, 16);
    if (valid && li == 0) ssh[h][j] = part + (float)ush[h * 264 + 256];
  }
  __syncthreads();

  if (tid < 64) {
    int head = tid >> 5, l2 = tid & 31;
    const float scale = 0.08838834764831845f; // 1/sqrt(128)
    float s = (l2 < 20) ? (msh[l2] ? -1e10f : ssh[head][l2] * scale) : -3.0e38f;
    float mx = s;
    for (int m = 16; m; m >>= 1) mx = fmaxf(mx, __shfl_xor(mx, m, 32));
    float e = (l2 < 20) ? __expf(s - mx) : 0.f;
    float sum = e;
    for (int m = 16; m; m >>= 1) sum += __shfl_xor(sum, m, 32);
    if (l2 < 20) ash[head][l2] = e / sum;
  }
  __syncthreads();

  {
    int p = tid;
    const _Float16* colp = (p < 128) ? &fsh[0][p] : &tesh[0][p - 128];
    float a0 = 0.f, a1 = 0.f;
#pragma unroll 5
    for (int j = 0; j < 20; j++) {
      float x = (float)colp[j * 136];
      a0 += ash[0][j] * x;
      a1 += ash[1][j] * x;
    }
    UY[(size_t)row * 520 + p] = (_Float16)a0;
    UY[(size_t)row * 520 + 260 + p] = (_Float16)a1;
  }
  if (tid < 8) {
    int p = (tid < 4) ? (256 + tid) : (512 + tid);
    _Float16 v = (_Float16)((tid == 0 || tid == 4) ? 1.f : 0.f);
    UY[(size_t)row * 520 + p] = v;
  }
}

__global__ __launch_bounds__(256, 8) void k_score_multi(
    ScoreJob ja, ScoreJob jb, const float* __restrict__ freq,
    const float* __restrict__ phase,
    const float* __restrict__ zp, _Float16* __restrict__ zh, int nzb)
{
  int b = blockIdx.x;
  if (b < ja.rows) { score_body(b, ja, freq, phase); return; }
  b -= ja.rows;
  if (b < jb.rows) { score_body(b, jb, freq, phase); return; }
  b -= jb.rows;
  if (b < nzb) {
    int i = b * 256 + threadIdx.x;
    const f4* zp4 = (const f4*)zp;
    f4 s = (f4)0.f;
#pragma unroll
    for (int p = 0; p < 8; p++) {
      f4 v = zp4[(size_t)p * 131072 + i];
      s.x += v.x; s.y += v.y; s.z += v.z; s.w += v.w;
    }
    h4 o = { (_Float16)s.x, (_Float16)s.y, (_Float16)s.z, (_Float16)s.w };
    ((h4*)zh)[i] = o;
  }
}

// ============ tail (P-GEMM + LN + MergeLayer) + MFMA-loss dispatcher ========

struct TailJob {
  const _Float16* U; const _Float16* F; const float* fcb; const float* srcv;
  const float* lng; const float* lnb;
  const _Float16* m1w; const float* m1b;
  const _Float16* m2w; const float* m2b;
  float* outp; int nblk;
};

__device__ void tail_body(int blk, const TailJob& J, const float* __restrict__ te0)
{
  __shared__ _Float16 Ps[64][264];
  __shared__ _Float16 Ss[64][136];
  __shared__ float redS[64][4], redQ[64][4];
  __shared__ float mrow[64], rrow[64];
  int tid = threadIdx.x;
  int wv = tid >> 6, lane = tid & 63;
  int lr = lane & 15, lk = lane >> 4;
  int row0 = blk * 64;
  int n0 = wv * 64;

  {
    const float4* sg = (const float4*)(J.srcv + (size_t)row0 * 128);
    for (int i = tid; i < 2048; i += 256) {
      int rr = i >> 5, c4 = i & 31;
      float4 v = sg[i];
      h4 hv = { (_Float16)v.x, (_Float16)v.y, (_Float16)v.z, (_Float16)v.w };
      *(h4*)&Ss[rr][c4 * 4] = hv;
    }
  }

  f4 acc[4][4];
#pragma unroll
  for (int i = 0; i < 4; i++)
#pragma unroll
    for (int j = 0; j < 4; j++) acc[i][j] = (f4)0.f;
  for (int kt = 0; kt < 17; kt++) {
    int kb = kt * 32 + lk * 8;
    bool ok = (kb + 8 <= 520);
    h8 af[4], bf[4];
#pragma unroll
    for (int i = 0; i < 4; i++)
      af[i] = ok ? *(const h8*)&J.U[(size_t)(row0 + i * 16 + lr) * 520 + kb]
                 : (h8)(_Float16)0.f;
#pragma unroll
    for (int j = 0; j < 4; j++)
      bf[j] = ok ? *(const h8*)&J.F[(size_t)(n0 + j * 16 + lr) * 520 + kb]
                 : (h8)(_Float16)0.f;
#pragma unroll
    for (int i = 0; i < 4; i++)
#pragma unroll
      for (int j = 0; j < 4; j++)
        acc[i][j] = __builtin_amdgcn_mfma_f32_16x16x32_f16(af[i], bf[j], acc[i][j], 0, 0, 0);
  }

#pragma unroll
  for (int i = 0; i < 4; i++) {
#pragma unroll
    for (int r = 0; r < 4; r++) {
      int row_l = i * 16 + lk * 4 + r;
      float rs = 0.f, rq = 0.f;
#pragma unroll
      for (int j = 0; j < 4; j++) {
        int c = n0 + j * 16 + lr;
        float q = (c < 128) ? J.srcv[(size_t)(row0 + row_l) * 128 + c] : te0[c - 128];
        float v = acc[i][j][r] + J.fcb[c] + q;
        acc[i][j][r] = v;
        rs += v; rq += v * v;
      }
      for (int m = 8; m; m >>= 1) {
        rs += __shfl_xor(rs, m, 16);
        rq += __shfl_xor(rq, m, 16);
      }
      if (lr == 0) { redS[row_l][wv] = rs; redQ[row_l][wv] = rq; }
    }
  }
  __syncthreads();
  if (tid < 64) {
    float s4 = redS[tid][0] + redS[tid][1] + redS[tid][2] + redS[tid][3];
    float q4 = redQ[tid][0] + redQ[tid][1] + redQ[tid][2] + redQ[tid][3];
    float mean = s4 * (1.0f / 256.0f);
    float var = q4 * (1.0f / 256.0f) - mean * mean;
    mrow[tid] = mean;
    rrow[tid] = rsqrtf(var + 1e-5f);
  }
  __syncthreads();
#pragma unroll
  for (int i = 0; i < 4; i++) {
#pragma unroll
    for (int r = 0; r < 4; r++) {
      int row_l = i * 16 + lk * 4 + r;
      float mean = mrow[row_l], rstd = rrow[row_l];
#pragma unroll
      for (int j = 0; j < 4; j++) {
        int c = n0 + j * 16 + lr;
        Ps[row_l][c] = (_Float16)((acc[i][j][r] - mean) * rstd * J.lng[c] + J.lnb[c]);
      }
    }
  }
  __syncthreads();

  int wm = wv >> 1, wn = wv & 1;
  f4 a2[2][4];
#pragma unroll
  for (int i = 0; i < 2; i++)
#pragma unroll
    for (int j = 0; j < 4; j++) a2[i][j] = (f4)0.f;
  for (int kk = 0; kk < 12; kk++) {
    int kb = kk * 32 + lk * 8;
    h8 af[2], bf[4];
#pragma unroll
    for (int i = 0; i < 2; i++) {
      int rl = wm * 32 + i * 16 + lr;
      af[i] = (kb < 256) ? *(const h8*)&Ps[rl][kb] : *(const h8*)&Ss[rl][kb - 256];
    }
#pragma unroll
    for (int j = 0; j < 4; j++)
      bf[j] = *(const h8*)&J.m1w[(size_t)(wn * 64 + j * 16 + lr) * 384 + kb];
#pragma unroll
    for (int i = 0; i < 2; i++)
#pragma unroll
      for (int j = 0; j < 4; j++)
        a2[i][j] = __builtin_amdgcn_mfma_f32_16x16x32_f16(af[i], bf[j], a2[i][j], 0, 0, 0);
  }
  __syncthreads();
#pragma unroll
  for (int i = 0; i < 2; i++) {
#pragma unroll
    for (int j = 0; j < 4; j++) {
      int c = wn * 64 + j * 16 + lr;
      float bz = J.m1b[c];
#pragma unroll
      for (int r = 0; r < 4; r++) {
        float v = a2[i][j][r] + bz;
        if (v < 0.f) v = 0.f;
        Ss[wm * 32 + i * 16 + lk * 4 + r][c] = (_Float16)v;
      }
    }
  }
  __syncthreads();

  f4 a3[2][4];
#pragma unroll
  for (int i = 0; i < 2; i++)
#pragma unroll
    for (int j = 0; j < 4; j++) a3[i][j] = (f4)0.f;
#pragma unroll
  for (int kk = 0; kk < 4; kk++) {
    int kb = kk * 32 + lk * 8;
    h8 af[2], bf[4];
#pragma unroll
    for (int i = 0; i < 2; i++)
      af[i] = *(const h8*)&Ss[wm * 32 + i * 16 + lr][kb];
#pragma unroll
    for (int j = 0; j < 4; j++)
      bf[j] = *(const h8*)&J.m2w[(size_t)(wn * 64 + j * 16 + lr) * 128 + kb];
#pragma unroll
    for (int i = 0; i < 2; i++)
#pragma unroll
      for (int j = 0; j < 4; j++)
        a3[i][j] = __builtin_amdgcn_mfma_f32_16x16x32_f16(af[i], bf[j], a3[i][j], 0, 0, 0);
  }
#pragma unroll
  for (int j = 0; j < 4; j++) {
    int c = wn * 64 + j * 16 + lr;
    float bz = J.m2b[c];
#pragma unroll
    for (int i = 0; i < 2; i++) {
#pragma unroll
      for (int r = 0; r < 4; r++) {
        int rl = wm * 32 + i * 16 + lk * 4 + r;
        J.outp[(size_t)(row0 + rl) * 128 + c] = a3[i][j][r] + bz;
      }
    }
  }
}

__device__ void loss_body(int b, const _Float16* __restrict__ z,
                          const float* __restrict__ adj, float* __restrict__ acc)
{
  int bi = b & 31, bj = b >> 5;
  int tid = threadIdx.x;
  int wv = tid >> 6, lane = tid & 63;
  int wm = wv >> 1, wn = wv & 1;
  int lr = lane & 15, lk = lane >> 4;
  int row0 = bi * 128 + wm * 64;
  int col0 = bj * 128 + wn * 64;

  f4 accf[4][4];
#pragma unroll
  for (int i = 0; i < 4; i++)
#pragma unroll
    for (int j = 0; j < 4; j++) accf[i][j] = (f4)0.f;

#pragma unroll
  for (int kk = 0; kk < 4; kk++) {
    int ko = kk * 32 + lk * 8;
    h8 af[4], bf[4];
#pragma unroll
    for (int i = 0; i < 4; i++)
      af[i] = *(const h8*)&z[(size_t)(row0 + i * 16 + lr) * 128 + ko];
#pragma unroll
    for (int j = 0; j < 4; j++)
      bf[j] = *(const h8*)&z[(size_t)(col0 + j * 16 + lr) * 128 + ko];
#pragma unroll
    for (int i = 0; i < 4; i++)
#pragma unroll
      for (int j = 0; j < 4; j++)
        accf[i][j] = __builtin_amdgcn_mfma_f32_16x16x32_f16(af[i], bf[j], accf[i][j], 0, 0, 0);
  }

  float lsum = 0.f;
#pragma unroll
  for (int i = 0; i < 4; i++) {
    int rbase = row0 + i * 16 + lk * 4;
#pragma unroll
    for (int r = 0; r < 4; r++) {
      const float* arow = adj + (size_t)(rbase + r) * 4096;
#pragma unroll
      for (int j = 0; j < 4; j++) {
        float x = accf[i][j][r];
        float s = 1.0f / (1.0f + __expf(-x));
        float d = arow[col0 + j * 16 + lr] - s;
        lsum += d * d;
      }
    }
  }
  for (int m = 32; m; m >>= 1) lsum += __shfl_xor(lsum, m, 64);
  if (lane == 0) atomicAdd(acc, lsum);
}

__global__ __launch_bounds__(256) void k_tail_loss(
    TailJob ja, TailJob jb, const float* __restrict__ te0,
    const _Float16* __restrict__ z, const float* __restrict__ adj,
    float* __restrict__ lacc, int nloss)
{
  int b = blockIdx.x;
  if (b < ja.nblk) { tail_body(b, ja, te0); return; }
  b -= ja.nblk;
  if (b < jb.nblk) { tail_body(b, jb, te0); return; }
  b -= jb.nblk;
  if (b < nloss) loss_body(b, z, adj, lacc);
}

// ---------------------------------------------------------------------------

extern "C" void kernel_launch(void* const* d_in, const int* in_sizes, int n_in,
                              void* d_out, int out_size, void* d_ws, size_t ws_size,
                              hipStream_t stream) {
  const float* src_feat  = (const float*)d_in[0];
  const float* src_t     = (const float*)d_in[1];
  const int*   ngh1_idx  = (const int*)d_in[2];
  const float* ngh1_t    = (const float*)d_in[3];
  const float* ngh1_feat = (const float*)d_in[4];
  const int*   ngh2_idx  = (const int*)d_in[5];
  const float* ngh2_t    = (const float*)d_in[6];
  const float* ngh2_feat = (const float*)d_in[7];
  const float* ae_x      = (const float*)d_in[8];
  const float* ae_adj    = (const float*)d_in[9];
  const float* W_lin     = (const float*)d_in[10];
  const float* b_lin     = (const float*)d_in[11];
  const float* freq      = (const float*)d_in[12];
  const float* phase     = (const float*)d_in[13];
  const float* wq        = (const float*)d_in[14];
  const float* wk        = (const float*)d_in[15];
  const float* wvp       = (const float*)d_in[16];
  const float* fcw       = (const float*)d_in[17];
  const float* fcb       = (const float*)d_in[18];
  const float* lng       = (const float*)d_in[19];
  const float* lnb       = (const float*)d_in[20];
  const float* m1w       = (const float*)d_in[21];
  const float* m1b       = (const float*)d_in[22];
  const float* m2w       = (const float*)d_in[23];
  const float* m2b       = (const float*)d_in[24];
  const float* W_gc      = (const float*)d_in[25];
  const float* b_gc      = (const float*)d_in[26];
  float* out = (float*)d_out;

  const int NB = 2048, NA = 40960;

  char* w = (char*)d_ws;
  size_t off = 0;
  auto alloc = [&](size_t bytes) -> void* {
    void* p = (void*)(w + off);
    off += (bytes + 255) & ~(size_t)255;
    return p;
  };
  float* te0    = (float*)alloc(128 * 4);
  float* linS   = (float*)alloc((size_t)NB * 128 * 4);
  float* lin1   = (float*)alloc((size_t)NA * 128 * 4);
  float* src_l1 = (float*)alloc((size_t)NB * 128 * 4);
  float* ngh_l1 = (float*)alloc((size_t)NA * 128 * 4);
  float* Mb     = (float*)alloc((size_t)4 * 32768 * 4);
  float* cbf    = (float*)alloc(4 * 256 * 4);
  _Float16* SWh = (_Float16*)alloc((size_t)3 * 520 * 128 * 2);
  float* cbU    = (float*)alloc(3 * 520 * 4);
  float* OW     = (float*)alloc((size_t)3 * 2 * 128 * 260 * 4);
  _Float16* Fh  = (_Float16*)alloc((size_t)3 * 256 * 520 * 2);
  _Float16* Wlinh = (_Float16*)alloc(16384 * 2);
  _Float16* m1wh  = (_Float16*)alloc((size_t)2 * 128 * 384 * 2);
  _Float16* m2wh  = (_Float16*)alloc((size_t)2 * 128 * 128 * 2);
  _Float16* WgcTh = (_Float16*)alloc(16384 * 2);
  _Float16* xwTh  = (_Float16*)alloc((size_t)4096 * 128 * 2);
  float* zpart    = (float*)alloc((size_t)8 * 4096 * 128 * 4);
  _Float16* zh    = (_Float16*)alloc((size_t)4096 * 128 * 2);
  float* lacc     = (float*)alloc(256);
  _Float16* UbufA = (_Float16*)alloc((size_t)NA * 520 * 2);
  _Float16* UbufB = (_Float16*)alloc((size_t)NB * 520 * 2);
  _Float16* UbufC = (_Float16*)alloc((size_t)NB * 520 * 2);

  // L1: independent prep
  k_prep_a<<<1936, 256, 0, stream>>>(phase, wq, wk, wvp, W_lin, b_lin, m1w, m2w,
                                     W_gc, te0, cbf, Mb, OW, Wlinh, m1wh, m2wh,
                                     WgcTh, lacc);
  // L2: dependent prep
  k_prep_b<<<2340, 256, 0, stream>>>(Mb, cbf, W_lin, b_lin, fcw, OW, SWh, cbU, Fh);

  GemmJob j0 = {};

  // L3: {linS, lin1, xwT}
  GemmJob jLinS = { src_feat,  Wlinh, b_lin,   linS,         128, 128, 128,
                    2048, 128, 128, 0, 128, 16, 1, 16 };
  GemmJob jLin1 = { ngh1_feat, Wlinh, b_lin,   lin1,         128, 128, 128,
                    40960, 128, 128, 0, 128, 320, 1, 320 };
  GemmJob jXwT  = { ae_x,      WgcTh, nullptr, (float*)xwTh, 128, 128, 4096,
                    4096, 128, 128, 2, 128, 32, 1, 32 };
  k_gemm_multi<<<368, 256, 0, stream>>>(jLinS, jLin1, jXwT, nullptr, nullptr);

  // L4: {U-A (A-resident), U-B, zb split-K=8}
  UJob uA = { lin1, SWh, cbU, UbufA, 320 };
  GemmJob jUB = { linS, SWh + 520 * 128,  cbU + 520, (float*)UbufB, 128, 128, 520,
                  2048, 520, 128, 1, 128, 16, 5, 80 };
  GemmJob jZB = { ae_adj, xwTh, b_gc, zpart, 4096, 4096, 128,
                  4096, 128, 4096, 0, 512, 32, 1, 256 };
  k_l3<<<320 + 80 + 256, 256, 0, stream>>>(uA, jUB, jZB);

  // L5: {score-A, score-B, zcomb}
  ScoreJob sA = { UbufA, ngh2_feat, ngh1_t, ngh2_t, ngh2_idx, NA };
  ScoreJob sB = { UbufB, lin1,      src_t,  ngh1_t, ngh1_idx, NB };
  k_score_multi<<<NA + NB + 512, 256, 0, stream>>>(sA, sB, freq, phase,
                                                   zpart, zh, 512);

  // L6: {tail-A, tail-B, loss}
  TailJob tA = { UbufA, Fh,             fcb, lin1, lng, lnb,
                 m1wh, m1b, m2wh, m2b, ngh_l1, NA / 64 };
  TailJob tB = { UbufB, Fh + 256 * 520, fcb, linS, lng, lnb,
                 m1wh, m1b, m2wh, m2b, src_l1, NB / 64 };
  k_tail_loss<<<NA / 64 + NB / 64 + 1024, 256, 0, stream>>>(
      tA, tB, te0, zh, ae_adj, lacc, 1024);

  // L7: {U-C, final loss write}
  GemmJob jUC = { src_l1, SWh + 2 * 520 * 128, cbU + 2 * 520, (float*)UbufC,
                  128, 128, 520, 2048, 520, 128, 1, 128, 16, 5, 80 };
  k_gemm_multi<<<81, 256, 0, stream>>>(jUC, j0, j0, lacc, out + (size_t)NB * 128);

  // L8: {score-C}
  ScoreJob sC = { UbufC, ngh_l1, src_t, ngh1_t, ngh1_idx, NB };
  ScoreJob s0 = {};
  k_score_multi<<<NB, 256, 0, stream>>>(sC, s0, freq, phase, nullptr, nullptr, 0);

  // L9: {tail-C} -> d_out
  TailJob tC = { UbufC, Fh + 2 * 256 * 520, fcb + 256, src_l1, lng + 256, lnb + 256,
                 m1wh + 128 * 384, m1b + 128, m2wh + 128 * 128, m2b + 128,
                 out, NB / 64 };
  TailJob t0 = {};
  k_tail_loss<<<NB / 64, 256, 0, stream>>>(tC, t0, te0, nullptr, nullptr,
                                           nullptr, 0);
}